// Round 12
// baseline (5517.244 us; speedup 1.0000x reference)
//
#include <hip/hip_runtime.h>
#include <stdint.h>

#define B_N 8192
#define D_IN 1024
#define D_HID 4096
#define D_LAT 256
#define K_CB 16384
#define VQ_NB (K_CB / 128)

typedef __attribute__((ext_vector_type(8))) short bf16x8;
typedef __attribute__((ext_vector_type(4))) float f32x4;

__device__ __forceinline__ unsigned short f2b(float v) {
  unsigned u = __float_as_uint(v);
  u += 0x7fffu + ((u >> 16) & 1u);  // RNE (finite values)
  return (unsigned short)(u >> 16);
}

// bijective XCD swizzle; requires gridDim.x*gridDim.y % 8 == 0
#define XCD_SWIZZLE(bx, by)                                   \
  {                                                           \
    const int gx_ = gridDim.x, n_ = gx_ * gridDim.y;          \
    const int wg_ = (by)*gx_ + (bx);                          \
    const int q_ = n_ >> 3;                                   \
    const int s_ = (wg_ & 7) * q_ + (wg_ >> 3);               \
    (bx) = s_ % gx_;                                          \
    (by) = s_ / gx_;                                          \
  }

// ---------- fp32 transpose [R][C] -> [C][R] ------------------------------
__global__ void transF_k(const float* __restrict__ in, float* __restrict__ out,
                         int R, int C) {
  __shared__ float t[32][33];
  const int tx = threadIdx.x & 31, ty4 = threadIdx.x >> 5;
  const int rb = blockIdx.y << 5, cb_ = blockIdx.x << 5;
#pragma unroll
  for (int r = 0; r < 4; ++r) {
    const int lr = (ty4 << 2) + r;
    t[lr][tx] = in[(size_t)(rb + lr) * C + cb_ + tx];
  }
  __syncthreads();
#pragma unroll
  for (int r = 0; r < 4; ++r) {
    const int lr = (ty4 << 2) + r;
    out[(size_t)(cb_ + lr) * R + rb + tx] = t[tx][lr];
  }
}

// ---------- 256x128 fp32 GEMM + bias + ReLU, A^T in, C^T out, chunked ----
// AT_ is [K][Ms_in] (reads at column mbase+m_local); CT is [N][Mc].
// Per-element fmaf chain over k IDENTICAL to rounds 4-11 -> bit-stable.
// All staging via global_load_lds; zero LDS scatter writes, zero conflicts.
__device__ __forceinline__ void enc_bigT_body(
    const float* __restrict__ AT_, const float* __restrict__ Bm,
    const float* __restrict__ bias, float* __restrict__ CT, int Ms_in,
    int mbase, int Mc, int N, int K) {
  __shared__ float As[16 * 256];
  __shared__ float Bs[16 * 128];
  const int tid = threadIdx.x;
  const int w = tid >> 6;
  const int tx = tid & 15, ty = tid >> 4;
  int bx = blockIdx.x, by = blockIdx.y;
  XCD_SWIZZLE(bx, by)
  const int m0 = by << 8, n0 = bx << 7;

  float acc[16][8];
#pragma unroll
  for (int i = 0; i < 16; ++i)
#pragma unroll
    for (int j = 0; j < 8; ++j) acc[i][j] = 0.0f;

  for (int k0 = 0; k0 < K; k0 += 16) {
#pragma unroll
    for (int r = 0; r < 4; ++r) {  // A^T tile: 16k x 256m, linear [k][m]
      const int f = tid + (r << 8);
      const float* gp =
          AT_ + (size_t)(k0 + (f >> 6)) * Ms_in + mbase + m0 + ((f & 63) << 2);
      __builtin_amdgcn_global_load_lds((const unsigned int*)gp,
                                       (unsigned int*)&As[(r << 10) + (w << 8)],
                                       16, 0, 0);
    }
#pragma unroll
    for (int r = 0; r < 2; ++r) {  // B tile: 16k x 128n, linear [k][n]
      const int f = tid + (r << 8);
      const float* gp = Bm + (size_t)(k0 + (f >> 5)) * N + n0 + ((f & 31) << 2);
      __builtin_amdgcn_global_load_lds((const unsigned int*)gp,
                                       (unsigned int*)&Bs[(r << 10) + (w << 8)],
                                       16, 0, 0);
    }
    __syncthreads();
#pragma unroll
    for (int kk = 0; kk < 16; ++kk) {
      float a[16], b[8];
#pragma unroll
      for (int q = 0; q < 4; ++q)
        *(float4*)(a + (q << 2)) =
            *(const float4*)(&As[kk * 256 + (q << 6) + (ty << 2)]);
      *(float4*)(b) = *(const float4*)(&Bs[kk * 128 + (tx << 2)]);
      *(float4*)(b + 4) = *(const float4*)(&Bs[kk * 128 + 64 + (tx << 2)]);
#pragma unroll
      for (int i = 0; i < 16; ++i)
#pragma unroll
        for (int j = 0; j < 8; ++j) acc[i][j] = fmaf(a[i], b[j], acc[i][j]);
    }
    __syncthreads();
  }

  float bb[8];
  *(float4*)(bb) = *(const float4*)(bias + n0 + (tx << 2));
  *(float4*)(bb + 4) = *(const float4*)(bias + n0 + 64 + (tx << 2));
#pragma unroll
  for (int j = 0; j < 8; ++j) {
    const int col = n0 + ((j >> 2) << 6) + (tx << 2) + (j & 3);
#pragma unroll
    for (int q = 0; q < 4; ++q) {
      float vq4[4];
#pragma unroll
      for (int r = 0; r < 4; ++r)
        vq4[r] = fmaxf(acc[(q << 2) + r][j] + bb[j], 0.0f);
      *(float4*)(CT + (size_t)col * Mc + m0 + (q << 6) + (ty << 2)) =
          *(float4*)(vq4);
    }
  }
}

__global__ __launch_bounds__(256, 2) void enc1_k(const float* AT_,
                                                 const float* B,
                                                 const float* bias, float* CT,
                                                 int Ms_in, int mbase, int Mc,
                                                 int N, int K) {
  enc_bigT_body(AT_, B, bias, CT, Ms_in, mbase, Mc, N, K);
}
__global__ __launch_bounds__(256, 2) void enc2_k(const float* AT_,
                                                 const float* B,
                                                 const float* bias, float* CT,
                                                 int Ms_in, int mbase, int Mc,
                                                 int N, int K) {
  enc_bigT_body(AT_, B, bias, CT, Ms_in, mbase, Mc, N, K);
}

// ---------- 128^2 fp32 GEMM + ReLU (fallback, row-major) ----------------
__global__ __launch_bounds__(256, 2) void enc_small_k(
    const float* __restrict__ A, const float* __restrict__ Bm,
    const float* __restrict__ bias, float* __restrict__ C, int M, int N,
    int K) {
  __shared__ float As[16][128];
  __shared__ float Bs[16][128];
  const int tid = threadIdx.x;
  const int tx = tid & 15, ty = tid >> 4;
  const int m0 = blockIdx.y << 7, n0 = blockIdx.x << 7;
  float acc[8][8];
#pragma unroll
  for (int i = 0; i < 8; ++i)
#pragma unroll
    for (int j = 0; j < 8; ++j) acc[i][j] = 0.0f;
  for (int k0 = 0; k0 < K; k0 += 16) {
#pragma unroll
    for (int r = 0; r < 2; ++r) {
      const int f = tid + (r << 8);
      const int m = f >> 2, kq = (f & 3) << 2;
      const float4 v = *(const float4*)(A + (size_t)(m0 + m) * K + k0 + kq);
      As[kq + 0][m] = v.x; As[kq + 1][m] = v.y;
      As[kq + 2][m] = v.z; As[kq + 3][m] = v.w;
    }
#pragma unroll
    for (int r = 0; r < 2; ++r) {
      const int f = tid + (r << 8);
      const int k = f >> 5, nq = (f & 31) << 2;
      *(float4*)(&Bs[k][nq]) =
          *(const float4*)(Bm + (size_t)(k0 + k) * N + n0 + nq);
    }
    __syncthreads();
#pragma unroll
    for (int kk = 0; kk < 16; ++kk) {
      float a[8], b[8];
      *(float4*)(a) = *(const float4*)(&As[kk][ty << 2]);
      *(float4*)(a + 4) = *(const float4*)(&As[kk][64 + (ty << 2)]);
      *(float4*)(b) = *(const float4*)(&Bs[kk][tx << 2]);
      *(float4*)(b + 4) = *(const float4*)(&Bs[kk][64 + (tx << 2)]);
#pragma unroll
      for (int i = 0; i < 8; ++i)
#pragma unroll
        for (int j = 0; j < 8; ++j) acc[i][j] = fmaf(a[i], b[j], acc[i][j]);
    }
    __syncthreads();
  }
  float bb[8];
  *(float4*)(bb) = *(const float4*)(bias + n0 + (tx << 2));
  *(float4*)(bb + 4) = *(const float4*)(bias + n0 + 64 + (tx << 2));
#pragma unroll
  for (int i = 0; i < 8; ++i) {
    const int row = m0 + ((i < 4) ? (ty << 2) + i : 64 + (ty << 2) + i - 4);
    float vrow[8];
#pragma unroll
    for (int j = 0; j < 8; ++j) vrow[j] = fmaxf(acc[i][j] + bb[j], 0.0f);
    *(float4*)(C + (size_t)row * N + n0 + (tx << 2)) = *(float4*)(vrow);
    *(float4*)(C + (size_t)row * N + n0 + 64 + (tx << 2)) = *(float4*)(vrow + 4);
  }
}

// ---------- eW3 split-K=8 partial; AT: A^T [K][Mstr] via global_load_lds --
template <bool AT>
__global__ __launch_bounds__(256, 2) void enc3_part_k(
    const float* __restrict__ A, const float* __restrict__ B,
    float* __restrict__ P, int M, int K, int Mstr) {
  __shared__ float As[16 * 128];
  __shared__ float Bs[16 * 128];
  const int tid = threadIdx.x;
  const int w = tid >> 6;
  const int tx = tid & 15, ty = tid >> 4;
  const int m0 = blockIdx.y << 7, n0 = blockIdx.x << 7;
  const int s = blockIdx.z;
  const int kbeg = s * (K >> 3), kend = kbeg + (K >> 3);
  float acc[8][8];
#pragma unroll
  for (int i = 0; i < 8; ++i)
#pragma unroll
    for (int j = 0; j < 8; ++j) acc[i][j] = 0.0f;
  for (int k0 = kbeg; k0 < kend; k0 += 16) {
    if (AT) {
#pragma unroll
      for (int r = 0; r < 2; ++r) {  // 16k x 128m, linear [k][m]
        const int f = tid + (r << 8);
        const float* gp =
            A + (size_t)(k0 + (f >> 5)) * Mstr + m0 + ((f & 31) << 2);
        __builtin_amdgcn_global_load_lds(
            (const unsigned int*)gp, (unsigned int*)&As[(r << 10) + (w << 8)],
            16, 0, 0);
      }
    } else {
#pragma unroll
      for (int r = 0; r < 2; ++r) {
        const int f = tid + (r << 8);
        const int m = f >> 2, kq = (f & 3) << 2;
        const float4 v = *(const float4*)(A + (size_t)(m0 + m) * K + k0 + kq);
        As[(kq + 0) * 128 + m] = v.x; As[(kq + 1) * 128 + m] = v.y;
        As[(kq + 2) * 128 + m] = v.z; As[(kq + 3) * 128 + m] = v.w;
      }
    }
#pragma unroll
    for (int r = 0; r < 2; ++r) {  // B [K][256] rows: lane-linear
      const int f = tid + (r << 8);
      const float* gp = B + (size_t)(k0 + (f >> 5)) * D_LAT + n0 + ((f & 31) << 2);
      __builtin_amdgcn_global_load_lds((const unsigned int*)gp,
                                       (unsigned int*)&Bs[(r << 10) + (w << 8)],
                                       16, 0, 0);
    }
    __syncthreads();
#pragma unroll
    for (int kk = 0; kk < 16; ++kk) {
      float a[8], b[8];
      *(float4*)(a) = *(const float4*)(&As[kk * 128 + (ty << 2)]);
      *(float4*)(a + 4) = *(const float4*)(&As[kk * 128 + 64 + (ty << 2)]);
      *(float4*)(b) = *(const float4*)(&Bs[kk * 128 + (tx << 2)]);
      *(float4*)(b + 4) = *(const float4*)(&Bs[kk * 128 + 64 + (tx << 2)]);
#pragma unroll
      for (int i = 0; i < 8; ++i)
#pragma unroll
        for (int j = 0; j < 8; ++j) acc[i][j] = fmaf(a[i], b[j], acc[i][j]);
    }
    __syncthreads();
  }
  float* Ps = P + (size_t)s * M * D_LAT;
#pragma unroll
  for (int i = 0; i < 8; ++i) {
    const int row = m0 + ((i < 4) ? (ty << 2) + i : 64 + (ty << 2) + i - 4);
    *(float4*)(Ps + (size_t)row * D_LAT + n0 + (tx << 2)) = *(float4*)(&acc[i][0]);
    *(float4*)(Ps + (size_t)row * D_LAT + n0 + 64 + (tx << 2)) = *(float4*)(&acc[i][4]);
  }
}

// combine 8 partials + bias, tanh -> z
__global__ void enc3_comb_k(const float* __restrict__ P,
                            const float* __restrict__ bias,
                            float* __restrict__ z, int M) {
  const size_t i4 = (size_t)blockIdx.x * blockDim.x + threadIdx.x;
  const size_t tot = (size_t)M * (D_LAT / 4);
  if (i4 >= tot) return;
  const size_t sstr = (size_t)M * (D_LAT / 4);
  const float4* Pv = (const float4*)P;
  float sx = 0.f, sy = 0.f, sz = 0.f, sw = 0.f;
#pragma unroll
  for (int s = 0; s < 8; ++s) {
    const float4 v = Pv[i4 + (size_t)s * sstr];
    sx += v.x; sy += v.y; sz += v.z; sw += v.w;
  }
  const int col = (int)((i4 << 2) & (D_LAT - 1));
  const float4 bb = *(const float4*)(bias + col);
  float4 o;
  o.x = tanhf(sx + bb.x);
  o.y = tanhf(sy + bb.y);
  o.z = tanhf(sz + bb.z);
  o.w = tanhf(sw + bb.w);
  ((float4*)z)[i4] = o;
}

// ---------- VQ distance+argmin, 256x128, zT/cbT inputs, atomic-free ------
__global__ __launch_bounds__(256, 2) void vq_k256(
    const float* __restrict__ zT, const float* __restrict__ cbT,
    const float* __restrict__ zz, const float* __restrict__ ee,
    unsigned long long* __restrict__ keys2) {
  __shared__ float As[16 * 256];
  __shared__ float Bs[16 * 128];
  const int tid = threadIdx.x;
  const int w = tid >> 6;
  const int tx = tid & 15, ty = tid >> 4;
  int bx = blockIdx.x, by = blockIdx.y;
  XCD_SWIZZLE(bx, by)
  const int m0 = by << 8, n0 = bx << 7;

  float acc[16][8];
#pragma unroll
  for (int i = 0; i < 16; ++i)
#pragma unroll
    for (int j = 0; j < 8; ++j) acc[i][j] = 0.0f;

  for (int k0 = 0; k0 < D_LAT; k0 += 16) {
#pragma unroll
    for (int r = 0; r < 4; ++r) {  // z^T [256][B_N]: 16k x 256m
      const int f = tid + (r << 8);
      const float* gp = zT + (size_t)(k0 + (f >> 6)) * B_N + m0 + ((f & 63) << 2);
      __builtin_amdgcn_global_load_lds((const unsigned int*)gp,
                                       (unsigned int*)&As[(r << 10) + (w << 8)],
                                       16, 0, 0);
    }
#pragma unroll
    for (int r = 0; r < 2; ++r) {  // cb^T [256][K_CB]: 16k x 128n
      const int f = tid + (r << 8);
      const float* gp = cbT + (size_t)(k0 + (f >> 5)) * K_CB + n0 + ((f & 31) << 2);
      __builtin_amdgcn_global_load_lds((const unsigned int*)gp,
                                       (unsigned int*)&Bs[(r << 10) + (w << 8)],
                                       16, 0, 0);
    }
    __syncthreads();
#pragma unroll
    for (int kk = 0; kk < 16; ++kk) {
      float a[16], b[8];
#pragma unroll
      for (int q = 0; q < 4; ++q)
        *(float4*)(a + (q << 2)) =
            *(const float4*)(&As[kk * 256 + (q << 6) + (ty << 2)]);
      *(float4*)(b) = *(const float4*)(&Bs[kk * 128 + (tx << 2)]);
      *(float4*)(b + 4) = *(const float4*)(&Bs[kk * 128 + 64 + (tx << 2)]);
#pragma unroll
      for (int i = 0; i < 16; ++i)
#pragma unroll
        for (int j = 0; j < 8; ++j) acc[i][j] = fmaf(a[i], b[j], acc[i][j]);
    }
    __syncthreads();
  }

  // EXACT reference fp32 expression: d = fl(fl(zz+ee) - 2*dot); first-index
  // tie-break preserved by packed u64 (ordered bits << 32 | col) min.
  float zr[16];
#pragma unroll
  for (int i = 0; i < 16; ++i)
    zr[i] = zz[m0 + ((i >> 2) << 6) + (ty << 2) + (i & 3)];
  float ev[8];
  *(float4*)(ev) = *(const float4*)(ee + n0 + (tx << 2));
  *(float4*)(ev + 4) = *(const float4*)(ee + n0 + 64 + (tx << 2));
#pragma unroll
  for (int i = 0; i < 16; ++i) {
    unsigned long long bk = ~0ull;
#pragma unroll
    for (int j = 0; j < 8; ++j) {
      const int col = n0 + ((j >> 2) << 6) + (tx << 2) + (j & 3);
      const float t = zr[i] + ev[j];
      const float d = t - 2.0f * acc[i][j];
      unsigned u = __float_as_uint(d);
      u = (u & 0x80000000u) ? ~u : (u | 0x80000000u);
      const unsigned long long key = ((unsigned long long)u << 32) | (unsigned)col;
      bk = key < bk ? key : bk;
    }
#pragma unroll
    for (int s = 1; s <= 8; s <<= 1) {
      const unsigned long long o = __shfl_xor(bk, s);
      if (o < bk) bk = o;
    }
    if (tx == 0) {
      const int row = m0 + ((i >> 2) << 6) + (ty << 2) + (i & 3);
      keys2[(size_t)row * VQ_NB + bx] = bk;
    }
  }
}

__global__ void vq_red_k(const unsigned long long* __restrict__ keys2,
                         unsigned long long* __restrict__ keys) {
  const int row = (int)((blockIdx.x * blockDim.x + threadIdx.x) >> 6);
  const int lane = threadIdx.x & 63;
  if (row >= B_N) return;
  unsigned long long a = keys2[(size_t)row * VQ_NB + lane];
  const unsigned long long b = keys2[(size_t)row * VQ_NB + 64 + lane];
  a = b < a ? b : a;
#pragma unroll
  for (int s = 32; s; s >>= 1) {
    const unsigned long long o = __shfl_xor(a, s);
    a = o < a ? o : a;
  }
  if (lane == 0) keys[row] = a;
}

// ---------------- bf16 MFMA GEMM (decoder), m97 structure ----------------
template <int EPI>
__device__ __forceinline__ void mgemm_body(
    const unsigned short* __restrict__ A, const unsigned short* __restrict__ Bt,
    const float* __restrict__ bias, void* __restrict__ Cout, int M, int N,
    int K, const float* __restrict__ xref, double* __restrict__ accums) {
  __shared__ __align__(16) unsigned short As[4096];
  __shared__ __align__(16) unsigned short Bs[4096];
  const int tid = threadIdx.x;
  const int w = tid >> 6, l = tid & 63;
  const int wr = w >> 1, wc = w & 1;
  const int g = l >> 4, tx = l & 15;
  int bx = blockIdx.x, by = blockIdx.y;
  XCD_SWIZZLE(bx, by)
  const int m0 = by << 7, n0 = bx << 7;

  f32x4 acc[4][4];
#pragma unroll
  for (int i = 0; i < 4; ++i)
#pragma unroll
    for (int j = 0; j < 4; ++j) acc[i][j] = (f32x4)0.0f;

  for (int k0 = 0; k0 < K; k0 += 32) {
#pragma unroll
    for (int c = 0; c < 2; ++c) {
      const int f = tid + (c << 8);
      const unsigned short* ga =
          A + (size_t)(m0 + (f >> 2)) * K + k0 + ((f & 3) << 3);
      __builtin_amdgcn_global_load_lds((const unsigned int*)ga,
                                       (unsigned int*)&As[(c << 11) + (w << 9)],
                                       16, 0, 0);
      const unsigned short* gb =
          Bt + (size_t)(n0 + (f >> 2)) * K + k0 + ((f & 3) << 3);
      __builtin_amdgcn_global_load_lds((const unsigned int*)gb,
                                       (unsigned int*)&Bs[(c << 11) + (w << 9)],
                                       16, 0, 0);
    }
    __syncthreads();
    bf16x8 af[4], bfv[4];
#pragma unroll
    for (int f = 0; f < 4; ++f) {
      af[f] = *(const bf16x8*)&As[((wr << 6) + (f << 4) + tx) * 32 + (g << 3)];
      bfv[f] = *(const bf16x8*)&Bs[((wc << 6) + (f << 4) + tx) * 32 + (g << 3)];
    }
#pragma unroll
    for (int fm = 0; fm < 4; ++fm)
#pragma unroll
      for (int fn = 0; fn < 4; ++fn)
        acc[fm][fn] = __builtin_amdgcn_mfma_f32_16x16x32_bf16(
            af[fm], bfv[fn], acc[fm][fn], 0, 0, 0);
    __syncthreads();
  }

  double lsum = 0.0;
#pragma unroll
  for (int fm = 0; fm < 4; ++fm) {
    const int row0 = m0 + (wr << 6) + (fm << 4) + (g << 2);
#pragma unroll
    for (int fn = 0; fn < 4; ++fn) {
      const int col = n0 + (wc << 6) + (fn << 4) + tx;
      const float bb = bias[col];
#pragma unroll
      for (int r = 0; r < 4; ++r) {
        float v = acc[fm][fn][r] + bb;
        if (EPI == 0) {
          v = fmaxf(v, 0.0f);
          ((unsigned short*)Cout)[(size_t)(row0 + r) * N + col] = f2b(v);
        } else {
          const float xr = xref[(size_t)(row0 + r) * N + col];
          const float df = v - xr;
          lsum += (double)df * (double)df;
          ((float*)Cout)[(size_t)(row0 + r) * N + col] = v;
        }
      }
    }
  }
  if (EPI == 1) {
#pragma unroll
    for (int o = 32; o; o >>= 1) lsum += __shfl_down(lsum, o);
    if (l == 0) atomicAdd(accums + 1, lsum);
  }
}

__global__ __launch_bounds__(256, 2) void dec1_k(const unsigned short* A,
                                                 const unsigned short* Bt,
                                                 const float* bias,
                                                 unsigned short* C, int M,
                                                 int N, int K) {
  mgemm_body<0>(A, Bt, bias, C, M, N, K, nullptr, nullptr);
}
__global__ __launch_bounds__(256, 2) void dec2_k(const unsigned short* A,
                                                 const unsigned short* Bt,
                                                 const float* bias,
                                                 unsigned short* C, int M,
                                                 int N, int K) {
  mgemm_body<0>(A, Bt, bias, C, M, N, K, nullptr, nullptr);
}
__global__ __launch_bounds__(256, 2) void dec3_k(const unsigned short* A,
                                                 const unsigned short* Bt,
                                                 const float* bias, float* C,
                                                 int M, int N, int K,
                                                 const float* xref,
                                                 double* accums) {
  mgemm_body<1>(A, Bt, bias, C, M, N, K, xref, accums);
}

// transpose-cast fp32 [K][N] -> bf16 [N][K]
__global__ void castT_k(const float* __restrict__ W,
                        unsigned short* __restrict__ out, int K, int N) {
  __shared__ float t[32][33];
  const int tx = threadIdx.x & 31, ty4 = threadIdx.x >> 5;
  const int nb = blockIdx.x << 5, kb = blockIdx.y << 5;
#pragma unroll
  for (int r = 0; r < 4; ++r) {
    const int k = (ty4 << 2) + r;
    t[k][tx] = W[(size_t)(kb + k) * N + nb + tx];
  }
  __syncthreads();
#pragma unroll
  for (int r = 0; r < 4; ++r) {
    const int n = (ty4 << 2) + r;
    out[(size_t)(nb + n) * K + kb + tx] = f2b(t[tx][n]);
  }
}

__global__ void rowsumsq(const float* __restrict__ v, float* __restrict__ out,
                         int rows) {
  const int w = (int)((blockIdx.x * blockDim.x + threadIdx.x) >> 6);
  const int lane = threadIdx.x & 63;
  if (w >= rows) return;
  const float4 x = *(const float4*)(v + (size_t)w * 256 + (lane << 2));
  float s = ((x.x * x.x + x.y * x.y) + x.z * x.z) + x.w * x.w;
#pragma unroll
  for (int o = 32; o; o >>= 1) s += __shfl_down(s, o);
  if (lane == 0) out[w] = s;
}

__global__ void finalize_vq(const unsigned long long* __restrict__ keys,
                            const float* __restrict__ z,
                            const float* __restrict__ cb,
                            unsigned short* __restrict__ qst_bf,
                            float* __restrict__ tok, int* __restrict__ counts,
                            double* __restrict__ accums) {
  const int row = (int)((blockIdx.x * blockDim.x + threadIdx.x) >> 6);
  const int lane = threadIdx.x & 63;
  if (row >= B_N) return;
  const int idx = (int)(keys[row] & 0xffffffffull);
  const float4 zv = *(const float4*)(z + (size_t)row * 256 + (lane << 2));
  const float4 evv = *(const float4*)(cb + (size_t)idx * 256 + (lane << 2));
  float4 q;
  double s = 0.0;
  float d;
  d = evv.x - zv.x; q.x = zv.x + d; s += (double)d * (double)d;
  d = evv.y - zv.y; q.y = zv.y + d; s += (double)d * (double)d;
  d = evv.z - zv.z; q.z = zv.z + d; s += (double)d * (double)d;
  d = evv.w - zv.w; q.w = zv.w + d; s += (double)d * (double)d;
  ushort4 qb;
  qb.x = f2b(q.x); qb.y = f2b(q.y); qb.z = f2b(q.z); qb.w = f2b(q.w);
  *(ushort4*)(qst_bf + (size_t)row * 256 + (lane << 2)) = qb;
#pragma unroll
  for (int o = 32; o; o >>= 1) s += __shfl_down(s, o);
  if (lane == 0) {
    atomicAdd(accums + 0, s);
    tok[row] = (float)idx;
    atomicAdd(counts + idx, 1);
  }
}

__global__ void finalize_scalars(const int* __restrict__ counts,
                                 const double* __restrict__ accums,
                                 float* __restrict__ outs) {
  __shared__ double red[256];
  double h = 0.0;
  for (int k = threadIdx.x; k < K_CB; k += 256) {
    const float p = (float)counts[k] * (1.0f / 8192.0f);
    const float t = p * logf(p + 1e-10f);
    h += (double)t;
  }
  red[threadIdx.x] = h;
  __syncthreads();
  for (int s = 128; s; s >>= 1) {
    if ((int)threadIdx.x < s) red[threadIdx.x] += red[threadIdx.x + s];
    __syncthreads();
  }
  if (threadIdx.x == 0) {
    const float perp = expf((float)(-red[0]));
    const float m1 = (float)(accums[0] * (1.0 / ((double)B_N * (double)D_LAT)));
    const float vq = m1 + 0.25f * m1;
    const float rl = (float)(accums[1] * (1.0 / ((double)B_N * (double)D_IN)));
    outs[0] = vq;
    outs[1] = rl;
    outs[2] = vq + rl;
    outs[3] = perp;
  }
}

extern "C" void kernel_launch(void* const* d_in, const int* in_sizes, int n_in,
                              void* d_out, int out_size, void* d_ws,
                              size_t ws_size, hipStream_t stream) {
  (void)in_sizes; (void)n_in; (void)out_size;
  const float* x   = (const float*)d_in[0];
  const float* eW1 = (const float*)d_in[1];
  const float* eb1 = (const float*)d_in[2];
  const float* eW2 = (const float*)d_in[3];
  const float* eb2 = (const float*)d_in[4];
  const float* eW3 = (const float*)d_in[5];
  const float* eb3 = (const float*)d_in[6];
  const float* cb  = (const float*)d_in[7];
  const float* dW1 = (const float*)d_in[8];
  const float* db1 = (const float*)d_in[9];
  const float* dW2 = (const float*)d_in[10];
  const float* db2 = (const float*)d_in[11];
  const float* dW3 = (const float*)d_in[12];
  const float* db3 = (const float*)d_in[13];
  float* out = (float*)d_out;

  char* ws = (char*)d_ws;
  const size_t OFF_Z      = 0;
  const size_t OFF_EEV    = OFF_Z + (size_t)B_N * D_LAT * 4;
  const size_t OFF_ZZV    = OFF_EEV + (size_t)K_CB * 4;
  const size_t OFF_KEYS   = OFF_ZZV + (size_t)B_N * 4;
  const size_t OFF_COUNTS = OFF_KEYS + (size_t)B_N * 8;
  const size_t OFF_ACC    = OFF_COUNTS + (size_t)K_CB * 4;
  const size_t OFF_QB     = OFF_ACC + 256;
  const size_t OFF_K2     = OFF_QB + (size_t)B_N * D_LAT * 2;
  const size_t OFF_H      = OFF_K2 + (size_t)B_N * VQ_NB * 8;

  float* z    = (float*)(ws + OFF_Z);
  float* eev  = (float*)(ws + OFF_EEV);
  float* zzv  = (float*)(ws + OFF_ZZV);
  unsigned long long* keys = (unsigned long long*)(ws + OFF_KEYS);
  int* counts = (int*)(ws + OFF_COUNTS);
  double* accums = (double*)(ws + OFF_ACC);
  unsigned short* qst_bf = (unsigned short*)(ws + OFF_QB);
  unsigned long long* keys2 = (unsigned long long*)(ws + OFF_K2);

  const size_t SZ_XT = (size_t)D_IN * B_N * 4;  // 32MB
  // A^T-path chunk: xT + 2 chunk buffers must fit.
  int cA = 0;
  for (int c = 8192; c >= 1024; c >>= 1)
    if (OFF_H + SZ_XT + 2ull * c * D_HID * 4 <= ws_size) { cA = c; break; }

  // Fallback row-major chunk (round-11 path):
  int c_enc = 256;
  for (int c = 8192; c >= 256; c >>= 1)
    if (OFF_H + 2ull * c * D_HID * 4 <= ws_size) { c_enc = c; break; }

  const size_t SZ_WB1 = (size_t)D_HID * D_LAT * 2;
  const size_t SZ_WB2 = (size_t)D_HID * D_HID * 2;
  const size_t SZ_WB3 = (size_t)D_IN * D_HID * 2;
  const size_t OFF_DECH = OFF_H + SZ_WB1 + SZ_WB2 + SZ_WB3;
  int c_dec = 128;
  for (int c = 8192; c >= 128; c >>= 1)
    if (OFF_DECH + 2ull * c * D_HID * 2 <= ws_size) { c_dec = c; break; }
  unsigned short* wB1 = (unsigned short*)(ws + OFF_H);
  unsigned short* wB2 = (unsigned short*)(ws + OFF_H + SZ_WB1);
  unsigned short* wB3 = (unsigned short*)(ws + OFF_H + SZ_WB1 + SZ_WB2);
  unsigned short* hbfA = (unsigned short*)(ws + OFF_DECH);
  unsigned short* hbfB = hbfA + (size_t)c_dec * D_HID;

  float* tok_out = out + (size_t)B_N * D_IN;
  float* scal_out = tok_out + B_N;

  hipMemsetAsync(counts, 0, (size_t)K_CB * 4, stream);
  hipMemsetAsync(accums, 0, 2 * sizeof(double), stream);

  rowsumsq<<<(K_CB * 64) / 256, 256, 0, stream>>>(cb, eev, K_CB);

  float* zT;
  float* cbT;
  if (cA >= 4096) {
    // ---- encoder, A^T-chained & chunked (bit-identical chain) ----
    float* xT = (float*)(ws + OFF_H);          // [1024][8192] 32MB
    float* hAT = xT + (size_t)D_IN * B_N;      // [4096][cA]
    float* hBT = hAT + (size_t)D_HID * cA;     // [4096][cA]
    float* P3 = hAT;                           // split-K partials (hAT dead)
    transF_k<<<dim3(D_IN / 32, B_N / 32), 256, 0, stream>>>(x, xT, B_N, D_IN);
    for (int c0 = 0; c0 < B_N; c0 += cA) {
      enc1_k<<<dim3(D_HID / 128, cA / 256), 256, 0, stream>>>(
          xT, eW1, eb1, hAT, B_N, c0, cA, D_HID, D_IN);
      enc2_k<<<dim3(D_HID / 128, cA / 256), 256, 0, stream>>>(
          hAT, eW2, eb2, hBT, cA, 0, cA, D_HID, D_HID);
      enc3_part_k<true><<<dim3(D_LAT / 128, cA / 128, 8), 256, 0, stream>>>(
          hBT, eW3, P3, cA, D_HID, cA);
      enc3_comb_k<<<(cA * (D_LAT / 4) + 255) / 256, 256, 0, stream>>>(
          P3, eb3, z + (size_t)c0 * D_LAT, cA);
    }
    zT = xT;                                    // 8MB (xT dead)
    cbT = xT + (size_t)D_LAT * B_N;             // 16MB
  } else {
    float* hA = (float*)(ws + OFF_H);
    float* hB = hA + (size_t)c_enc * D_HID;
    float* P3 = hA;
    for (int c0 = 0; c0 < B_N; c0 += c_enc) {
      const dim3 gH(D_HID / 128, c_enc / 128);
      enc_small_k<<<gH, 256, 0, stream>>>(x + (size_t)c0 * D_IN, eW1, eb1, hA,
                                          c_enc, D_HID, D_IN);
      enc_small_k<<<gH, 256, 0, stream>>>(hA, eW2, eb2, hB, c_enc, D_HID,
                                          D_HID);
      enc3_part_k<false><<<dim3(D_LAT / 128, c_enc / 128, 8), 256, 0, stream>>>(
          hB, eW3, P3, c_enc, D_HID, 0);
      enc3_comb_k<<<(c_enc * (D_LAT / 4) + 255) / 256, 256, 0, stream>>>(
          P3, eb3, z + (size_t)c0 * D_LAT, c_enc);
    }
    zT = hA;
    cbT = hB;
  }

  // ---- VQ prep: z^T, cb^T (into now-dead encoder buffers) ----
  transF_k<<<dim3(D_LAT / 32, B_N / 32), 256, 0, stream>>>(z, zT, B_N, D_LAT);
  transF_k<<<dim3(D_LAT / 32, K_CB / 32), 256, 0, stream>>>(cb, cbT, K_CB,
                                                            D_LAT);
  rowsumsq<<<(B_N * 64) / 256, 256, 0, stream>>>(z, zzv, B_N);

  // ---- VQ (atomic-free 2-stage) ----
  vq_k256<<<dim3(VQ_NB, B_N / 256), 256, 0, stream>>>(zT, cbT, zzv, eev, keys2);
  vq_red_k<<<(B_N * 64) / 256, 256, 0, stream>>>(keys2, keys);
  finalize_vq<<<(B_N * 64) / 256, 256, 0, stream>>>(keys, z, cb, qst_bf,
                                                    tok_out, counts, accums);

  // ---- decoder weight transpose-casts ----
  castT_k<<<dim3(D_HID / 32, D_LAT / 32), 256, 0, stream>>>(dW1, wB1, D_LAT, D_HID);
  castT_k<<<dim3(D_HID / 32, D_HID / 32), 256, 0, stream>>>(dW2, wB2, D_HID, D_HID);
  castT_k<<<dim3(D_IN / 32, D_HID / 32), 256, 0, stream>>>(dW3, wB3, D_HID, D_IN);

  // ---- decoder (bf16 MFMA) ----
  for (int c0 = 0; c0 < B_N; c0 += c_dec) {
    const dim3 gH(D_HID / 128, c_dec / 128);
    dec1_k<<<gH, 256, 0, stream>>>(qst_bf + (size_t)c0 * D_LAT, wB1, db1, hbfA,
                                   c_dec, D_HID, D_LAT);
    dec2_k<<<gH, 256, 0, stream>>>(hbfA, wB2, db2, hbfB, c_dec, D_HID, D_HID);
    dec3_k<<<dim3(D_IN / 128, c_dec / 128), 256, 0, stream>>>(
        hbfB, wB3, db3, out + (size_t)c0 * D_IN, c_dec, D_IN, D_HID,
        x + (size_t)c0 * D_IN, accums);
  }

  finalize_scalars<<<1, 256, 0, stream>>>(counts, accums, scal_out);
}

// Round 13
// 5271.672 us; speedup vs baseline: 1.0466x; 1.0466x over previous
//
#include <hip/hip_runtime.h>
#include <stdint.h>

#define B_N 8192
#define D_IN 1024
#define D_HID 4096
#define D_LAT 256
#define K_CB 16384
#define VQ_NB (K_CB / 128)

typedef __attribute__((ext_vector_type(8))) short bf16x8;
typedef __attribute__((ext_vector_type(4))) float f32x4;

__device__ __forceinline__ unsigned short f2b(float v) {
  unsigned u = __float_as_uint(v);
  u += 0x7fffu + ((u >> 16) & 1u);  // RNE (finite values)
  return (unsigned short)(u >> 16);
}

// bijective XCD swizzle; requires gridDim.x*gridDim.y % 8 == 0
#define XCD_SWIZZLE(bx, by)                                   \
  {                                                           \
    const int gx_ = gridDim.x, n_ = gx_ * gridDim.y;          \
    const int wg_ = (by)*gx_ + (bx);                          \
    const int q_ = n_ >> 3;                                   \
    const int s_ = (wg_ & 7) * q_ + (wg_ >> 3);               \
    (bx) = s_ % gx_;                                          \
    (by) = s_ / gx_;                                          \
  }

// ---------- fp32 transpose [R][C] -> [C][R] ------------------------------
__global__ void transF_k(const float* __restrict__ in, float* __restrict__ out,
                         int R, int C) {
  __shared__ float t[32][33];
  const int tx = threadIdx.x & 31, ty4 = threadIdx.x >> 5;
  const int rb = blockIdx.y << 5, cb_ = blockIdx.x << 5;
#pragma unroll
  for (int r = 0; r < 4; ++r) {
    const int lr = (ty4 << 2) + r;
    t[lr][tx] = in[(size_t)(rb + lr) * C + cb_ + tx];
  }
  __syncthreads();
#pragma unroll
  for (int r = 0; r < 4; ++r) {
    const int lr = (ty4 << 2) + r;
    out[(size_t)(cb_ + lr) * R + rb + tx] = t[tx][lr];
  }
}

// ---------- 256x128 fp32 GEMM + bias + ReLU, A^T in, C^T out, dbuf -------
// AT_ is [K][Ms_in] (reads at column mbase+m_local); CT is [N][Mc].
// Double-buffered LDS: one barrier per K-step; prefetch has a full compute
// phase to land. Per-element fmaf chain over k IDENTICAL to rounds 4-12.
__device__ __forceinline__ void enc_bigT_body(
    const float* __restrict__ AT_, const float* __restrict__ Bm,
    const float* __restrict__ bias, float* __restrict__ CT, int Ms_in,
    int mbase, int Mc, int N, int K) {
  __shared__ float As[2][16 * 256];
  __shared__ float Bs[2][16 * 128];
  const int tid = threadIdx.x;
  const int w = tid >> 6;
  const int tx = tid & 15, ty = tid >> 4;
  int bx = blockIdx.x, by = blockIdx.y;
  XCD_SWIZZLE(bx, by)
  const int m0 = by << 8, n0 = bx << 7;

  float acc[16][8];
#pragma unroll
  for (int i = 0; i < 16; ++i)
#pragma unroll
    for (int j = 0; j < 8; ++j) acc[i][j] = 0.0f;

  auto stage = [&](int buf, int k0) {
#pragma unroll
    for (int r = 0; r < 4; ++r) {  // A^T tile: 16k x 256m, linear [k][m]
      const int f = tid + (r << 8);
      const float* gp =
          AT_ + (size_t)(k0 + (f >> 6)) * Ms_in + mbase + m0 + ((f & 63) << 2);
      __builtin_amdgcn_global_load_lds(
          (const unsigned int*)gp,
          (unsigned int*)&As[buf][(r << 10) + (w << 8)], 16, 0, 0);
    }
#pragma unroll
    for (int r = 0; r < 2; ++r) {  // B tile: 16k x 128n, linear [k][n]
      const int f = tid + (r << 8);
      const float* gp = Bm + (size_t)(k0 + (f >> 5)) * N + n0 + ((f & 31) << 2);
      __builtin_amdgcn_global_load_lds(
          (const unsigned int*)gp,
          (unsigned int*)&Bs[buf][(r << 10) + (w << 8)], 16, 0, 0);
    }
  };

  stage(0, 0);
  const int nb = K >> 4;
  for (int t = 0; t < nb; ++t) {
    __syncthreads();  // drains buf[t&1] loads (vmcnt0) + prior compute done
    if (t + 1 < nb) stage((t + 1) & 1, (t + 1) << 4);
    const int cur = t & 1;
#pragma unroll
    for (int kk = 0; kk < 16; ++kk) {
      float a[16], b[8];
#pragma unroll
      for (int q = 0; q < 4; ++q)
        *(float4*)(a + (q << 2)) =
            *(const float4*)(&As[cur][kk * 256 + (q << 6) + (ty << 2)]);
      *(float4*)(b) = *(const float4*)(&Bs[cur][kk * 128 + (tx << 2)]);
      *(float4*)(b + 4) = *(const float4*)(&Bs[cur][kk * 128 + 64 + (tx << 2)]);
#pragma unroll
      for (int i = 0; i < 16; ++i)
#pragma unroll
        for (int j = 0; j < 8; ++j) acc[i][j] = fmaf(a[i], b[j], acc[i][j]);
    }
  }

  float bb[8];
  *(float4*)(bb) = *(const float4*)(bias + n0 + (tx << 2));
  *(float4*)(bb + 4) = *(const float4*)(bias + n0 + 64 + (tx << 2));
#pragma unroll
  for (int j = 0; j < 8; ++j) {
    const int col = n0 + ((j >> 2) << 6) + (tx << 2) + (j & 3);
#pragma unroll
    for (int q = 0; q < 4; ++q) {
      float vq4[4];
#pragma unroll
      for (int r = 0; r < 4; ++r)
        vq4[r] = fmaxf(acc[(q << 2) + r][j] + bb[j], 0.0f);
      *(float4*)(CT + (size_t)col * Mc + m0 + (q << 6) + (ty << 2)) =
          *(float4*)(vq4);
    }
  }
}

__global__ __launch_bounds__(256, 2) void enc1_k(const float* AT_,
                                                 const float* B,
                                                 const float* bias, float* CT,
                                                 int Ms_in, int mbase, int Mc,
                                                 int N, int K) {
  enc_bigT_body(AT_, B, bias, CT, Ms_in, mbase, Mc, N, K);
}
__global__ __launch_bounds__(256, 2) void enc2_k(const float* AT_,
                                                 const float* B,
                                                 const float* bias, float* CT,
                                                 int Ms_in, int mbase, int Mc,
                                                 int N, int K) {
  enc_bigT_body(AT_, B, bias, CT, Ms_in, mbase, Mc, N, K);
}

// ---------- 128^2 fp32 GEMM + ReLU (fallback, row-major) ----------------
__global__ __launch_bounds__(256, 2) void enc_small_k(
    const float* __restrict__ A, const float* __restrict__ Bm,
    const float* __restrict__ bias, float* __restrict__ C, int M, int N,
    int K) {
  __shared__ float As[16][128];
  __shared__ float Bs[16][128];
  const int tid = threadIdx.x;
  const int tx = tid & 15, ty = tid >> 4;
  const int m0 = blockIdx.y << 7, n0 = blockIdx.x << 7;
  float acc[8][8];
#pragma unroll
  for (int i = 0; i < 8; ++i)
#pragma unroll
    for (int j = 0; j < 8; ++j) acc[i][j] = 0.0f;
  for (int k0 = 0; k0 < K; k0 += 16) {
#pragma unroll
    for (int r = 0; r < 2; ++r) {
      const int f = tid + (r << 8);
      const int m = f >> 2, kq = (f & 3) << 2;
      const float4 v = *(const float4*)(A + (size_t)(m0 + m) * K + k0 + kq);
      As[kq + 0][m] = v.x; As[kq + 1][m] = v.y;
      As[kq + 2][m] = v.z; As[kq + 3][m] = v.w;
    }
#pragma unroll
    for (int r = 0; r < 2; ++r) {
      const int f = tid + (r << 8);
      const int k = f >> 5, nq = (f & 31) << 2;
      *(float4*)(&Bs[k][nq]) =
          *(const float4*)(Bm + (size_t)(k0 + k) * N + n0 + nq);
    }
    __syncthreads();
#pragma unroll
    for (int kk = 0; kk < 16; ++kk) {
      float a[8], b[8];
      *(float4*)(a) = *(const float4*)(&As[kk][ty << 2]);
      *(float4*)(a + 4) = *(const float4*)(&As[kk][64 + (ty << 2)]);
      *(float4*)(b) = *(const float4*)(&Bs[kk][tx << 2]);
      *(float4*)(b + 4) = *(const float4*)(&Bs[kk][64 + (tx << 2)]);
#pragma unroll
      for (int i = 0; i < 8; ++i)
#pragma unroll
        for (int j = 0; j < 8; ++j) acc[i][j] = fmaf(a[i], b[j], acc[i][j]);
    }
    __syncthreads();
  }
  float bb[8];
  *(float4*)(bb) = *(const float4*)(bias + n0 + (tx << 2));
  *(float4*)(bb + 4) = *(const float4*)(bias + n0 + 64 + (tx << 2));
#pragma unroll
  for (int i = 0; i < 8; ++i) {
    const int row = m0 + ((i < 4) ? (ty << 2) + i : 64 + (ty << 2) + i - 4);
    float vrow[8];
#pragma unroll
    for (int j = 0; j < 8; ++j) vrow[j] = fmaxf(acc[i][j] + bb[j], 0.0f);
    *(float4*)(C + (size_t)row * N + n0 + (tx << 2)) = *(float4*)(vrow);
    *(float4*)(C + (size_t)row * N + n0 + 64 + (tx << 2)) = *(float4*)(vrow + 4);
  }
}

// ---------- eW3 split-K=8 partial; AT: A^T [K][Mstr] via global_load_lds --
template <bool AT>
__global__ __launch_bounds__(256, 2) void enc3_part_k(
    const float* __restrict__ A, const float* __restrict__ B,
    float* __restrict__ P, int M, int K, int Mstr) {
  __shared__ float As[16 * 128];
  __shared__ float Bs[16 * 128];
  const int tid = threadIdx.x;
  const int w = tid >> 6;
  const int tx = tid & 15, ty = tid >> 4;
  const int m0 = blockIdx.y << 7, n0 = blockIdx.x << 7;
  const int s = blockIdx.z;
  const int kbeg = s * (K >> 3), kend = kbeg + (K >> 3);
  float acc[8][8];
#pragma unroll
  for (int i = 0; i < 8; ++i)
#pragma unroll
    for (int j = 0; j < 8; ++j) acc[i][j] = 0.0f;
  for (int k0 = kbeg; k0 < kend; k0 += 16) {
    if (AT) {
#pragma unroll
      for (int r = 0; r < 2; ++r) {  // 16k x 128m, linear [k][m]
        const int f = tid + (r << 8);
        const float* gp =
            A + (size_t)(k0 + (f >> 5)) * Mstr + m0 + ((f & 31) << 2);
        __builtin_amdgcn_global_load_lds(
            (const unsigned int*)gp, (unsigned int*)&As[(r << 10) + (w << 8)],
            16, 0, 0);
      }
    } else {
#pragma unroll
      for (int r = 0; r < 2; ++r) {
        const int f = tid + (r << 8);
        const int m = f >> 2, kq = (f & 3) << 2;
        const float4 v = *(const float4*)(A + (size_t)(m0 + m) * K + k0 + kq);
        As[(kq + 0) * 128 + m] = v.x; As[(kq + 1) * 128 + m] = v.y;
        As[(kq + 2) * 128 + m] = v.z; As[(kq + 3) * 128 + m] = v.w;
      }
    }
#pragma unroll
    for (int r = 0; r < 2; ++r) {  // B [K][256] rows: lane-linear
      const int f = tid + (r << 8);
      const float* gp = B + (size_t)(k0 + (f >> 5)) * D_LAT + n0 + ((f & 31) << 2);
      __builtin_amdgcn_global_load_lds((const unsigned int*)gp,
                                       (unsigned int*)&Bs[(r << 10) + (w << 8)],
                                       16, 0, 0);
    }
    __syncthreads();
#pragma unroll
    for (int kk = 0; kk < 16; ++kk) {
      float a[8], b[8];
      *(float4*)(a) = *(const float4*)(&As[kk * 128 + (ty << 2)]);
      *(float4*)(a + 4) = *(const float4*)(&As[kk * 128 + 64 + (ty << 2)]);
      *(float4*)(b) = *(const float4*)(&Bs[kk * 128 + (tx << 2)]);
      *(float4*)(b + 4) = *(const float4*)(&Bs[kk * 128 + 64 + (tx << 2)]);
#pragma unroll
      for (int i = 0; i < 8; ++i)
#pragma unroll
        for (int j = 0; j < 8; ++j) acc[i][j] = fmaf(a[i], b[j], acc[i][j]);
    }
    __syncthreads();
  }
  float* Ps = P + (size_t)s * M * D_LAT;
#pragma unroll
  for (int i = 0; i < 8; ++i) {
    const int row = m0 + ((i < 4) ? (ty << 2) + i : 64 + (ty << 2) + i - 4);
    *(float4*)(Ps + (size_t)row * D_LAT + n0 + (tx << 2)) = *(float4*)(&acc[i][0]);
    *(float4*)(Ps + (size_t)row * D_LAT + n0 + 64 + (tx << 2)) = *(float4*)(&acc[i][4]);
  }
}

// combine 8 partials + bias, tanh -> z
__global__ void enc3_comb_k(const float* __restrict__ P,
                            const float* __restrict__ bias,
                            float* __restrict__ z, int M) {
  const size_t i4 = (size_t)blockIdx.x * blockDim.x + threadIdx.x;
  const size_t tot = (size_t)M * (D_LAT / 4);
  if (i4 >= tot) return;
  const size_t sstr = (size_t)M * (D_LAT / 4);
  const float4* Pv = (const float4*)P;
  float sx = 0.f, sy = 0.f, sz = 0.f, sw = 0.f;
#pragma unroll
  for (int s = 0; s < 8; ++s) {
    const float4 v = Pv[i4 + (size_t)s * sstr];
    sx += v.x; sy += v.y; sz += v.z; sw += v.w;
  }
  const int col = (int)((i4 << 2) & (D_LAT - 1));
  const float4 bb = *(const float4*)(bias + col);
  float4 o;
  o.x = tanhf(sx + bb.x);
  o.y = tanhf(sy + bb.y);
  o.z = tanhf(sz + bb.z);
  o.w = tanhf(sw + bb.w);
  ((float4*)z)[i4] = o;
}

// ---------- VQ distance+argmin, 256x128, zT/cbT inputs, dbuf -------------
__global__ __launch_bounds__(256, 2) void vq_k256(
    const float* __restrict__ zT, const float* __restrict__ cbT,
    const float* __restrict__ zz, const float* __restrict__ ee,
    unsigned long long* __restrict__ keys2) {
  __shared__ float As[2][16 * 256];
  __shared__ float Bs[2][16 * 128];
  const int tid = threadIdx.x;
  const int w = tid >> 6;
  const int tx = tid & 15, ty = tid >> 4;
  int bx = blockIdx.x, by = blockIdx.y;
  XCD_SWIZZLE(bx, by)
  const int m0 = by << 8, n0 = bx << 7;

  float acc[16][8];
#pragma unroll
  for (int i = 0; i < 16; ++i)
#pragma unroll
    for (int j = 0; j < 8; ++j) acc[i][j] = 0.0f;

  auto stage = [&](int buf, int k0) {
#pragma unroll
    for (int r = 0; r < 4; ++r) {  // z^T [256][B_N]: 16k x 256m
      const int f = tid + (r << 8);
      const float* gp = zT + (size_t)(k0 + (f >> 6)) * B_N + m0 + ((f & 63) << 2);
      __builtin_amdgcn_global_load_lds(
          (const unsigned int*)gp,
          (unsigned int*)&As[buf][(r << 10) + (w << 8)], 16, 0, 0);
    }
#pragma unroll
    for (int r = 0; r < 2; ++r) {  // cb^T [256][K_CB]: 16k x 128n
      const int f = tid + (r << 8);
      const float* gp = cbT + (size_t)(k0 + (f >> 5)) * K_CB + n0 + ((f & 31) << 2);
      __builtin_amdgcn_global_load_lds(
          (const unsigned int*)gp,
          (unsigned int*)&Bs[buf][(r << 10) + (w << 8)], 16, 0, 0);
    }
  };

  stage(0, 0);
  const int nb = D_LAT >> 4;
  for (int t = 0; t < nb; ++t) {
    __syncthreads();
    if (t + 1 < nb) stage((t + 1) & 1, (t + 1) << 4);
    const int cur = t & 1;
#pragma unroll
    for (int kk = 0; kk < 16; ++kk) {
      float a[16], b[8];
#pragma unroll
      for (int q = 0; q < 4; ++q)
        *(float4*)(a + (q << 2)) =
            *(const float4*)(&As[cur][kk * 256 + (q << 6) + (ty << 2)]);
      *(float4*)(b) = *(const float4*)(&Bs[cur][kk * 128 + (tx << 2)]);
      *(float4*)(b + 4) = *(const float4*)(&Bs[cur][kk * 128 + 64 + (tx << 2)]);
#pragma unroll
      for (int i = 0; i < 16; ++i)
#pragma unroll
        for (int j = 0; j < 8; ++j) acc[i][j] = fmaf(a[i], b[j], acc[i][j]);
    }
  }

  // EXACT reference fp32 expression: d = fl(fl(zz+ee) - 2*dot); first-index
  // tie-break preserved by packed u64 (ordered bits << 32 | col) min.
  float zr[16];
#pragma unroll
  for (int i = 0; i < 16; ++i)
    zr[i] = zz[m0 + ((i >> 2) << 6) + (ty << 2) + (i & 3)];
  float ev[8];
  *(float4*)(ev) = *(const float4*)(ee + n0 + (tx << 2));
  *(float4*)(ev + 4) = *(const float4*)(ee + n0 + 64 + (tx << 2));
#pragma unroll
  for (int i = 0; i < 16; ++i) {
    unsigned long long bk = ~0ull;
#pragma unroll
    for (int j = 0; j < 8; ++j) {
      const int col = n0 + ((j >> 2) << 6) + (tx << 2) + (j & 3);
      const float t = zr[i] + ev[j];
      const float d = t - 2.0f * acc[i][j];
      unsigned u = __float_as_uint(d);
      u = (u & 0x80000000u) ? ~u : (u | 0x80000000u);
      const unsigned long long key = ((unsigned long long)u << 32) | (unsigned)col;
      bk = key < bk ? key : bk;
    }
#pragma unroll
    for (int s = 1; s <= 8; s <<= 1) {
      const unsigned long long o = __shfl_xor(bk, s);
      if (o < bk) bk = o;
    }
    if (tx == 0) {
      const int row = m0 + ((i >> 2) << 6) + (ty << 2) + (i & 3);
      keys2[(size_t)row * VQ_NB + bx] = bk;
    }
  }
}

__global__ void vq_red_k(const unsigned long long* __restrict__ keys2,
                         unsigned long long* __restrict__ keys) {
  const int row = (int)((blockIdx.x * blockDim.x + threadIdx.x) >> 6);
  const int lane = threadIdx.x & 63;
  if (row >= B_N) return;
  unsigned long long a = keys2[(size_t)row * VQ_NB + lane];
  const unsigned long long b = keys2[(size_t)row * VQ_NB + 64 + lane];
  a = b < a ? b : a;
#pragma unroll
  for (int s = 32; s; s >>= 1) {
    const unsigned long long o = __shfl_xor(a, s);
    a = o < a ? o : a;
  }
  if (lane == 0) keys[row] = a;
}

// ---------------- bf16 MFMA GEMM (decoder), m97 structure ----------------
template <int EPI>
__device__ __forceinline__ void mgemm_body(
    const unsigned short* __restrict__ A, const unsigned short* __restrict__ Bt,
    const float* __restrict__ bias, void* __restrict__ Cout, int M, int N,
    int K, const float* __restrict__ xref, double* __restrict__ accums) {
  __shared__ __align__(16) unsigned short As[4096];
  __shared__ __align__(16) unsigned short Bs[4096];
  const int tid = threadIdx.x;
  const int w = tid >> 6, l = tid & 63;
  const int wr = w >> 1, wc = w & 1;
  const int g = l >> 4, tx = l & 15;
  int bx = blockIdx.x, by = blockIdx.y;
  XCD_SWIZZLE(bx, by)
  const int m0 = by << 7, n0 = bx << 7;

  f32x4 acc[4][4];
#pragma unroll
  for (int i = 0; i < 4; ++i)
#pragma unroll
    for (int j = 0; j < 4; ++j) acc[i][j] = (f32x4)0.0f;

  for (int k0 = 0; k0 < K; k0 += 32) {
#pragma unroll
    for (int c = 0; c < 2; ++c) {
      const int f = tid + (c << 8);
      const unsigned short* ga =
          A + (size_t)(m0 + (f >> 2)) * K + k0 + ((f & 3) << 3);
      __builtin_amdgcn_global_load_lds((const unsigned int*)ga,
                                       (unsigned int*)&As[(c << 11) + (w << 9)],
                                       16, 0, 0);
      const unsigned short* gb =
          Bt + (size_t)(n0 + (f >> 2)) * K + k0 + ((f & 3) << 3);
      __builtin_amdgcn_global_load_lds((const unsigned int*)gb,
                                       (unsigned int*)&Bs[(c << 11) + (w << 9)],
                                       16, 0, 0);
    }
    __syncthreads();
    bf16x8 af[4], bfv[4];
#pragma unroll
    for (int f = 0; f < 4; ++f) {
      af[f] = *(const bf16x8*)&As[((wr << 6) + (f << 4) + tx) * 32 + (g << 3)];
      bfv[f] = *(const bf16x8*)&Bs[((wc << 6) + (f << 4) + tx) * 32 + (g << 3)];
    }
#pragma unroll
    for (int fm = 0; fm < 4; ++fm)
#pragma unroll
      for (int fn = 0; fn < 4; ++fn)
        acc[fm][fn] = __builtin_amdgcn_mfma_f32_16x16x32_bf16(
            af[fm], bfv[fn], acc[fm][fn], 0, 0, 0);
    __syncthreads();
  }

  double lsum = 0.0;
#pragma unroll
  for (int fm = 0; fm < 4; ++fm) {
    const int row0 = m0 + (wr << 6) + (fm << 4) + (g << 2);
#pragma unroll
    for (int fn = 0; fn < 4; ++fn) {
      const int col = n0 + (wc << 6) + (fn << 4) + tx;
      const float bb = bias[col];
#pragma unroll
      for (int r = 0; r < 4; ++r) {
        float v = acc[fm][fn][r] + bb;
        if (EPI == 0) {
          v = fmaxf(v, 0.0f);
          ((unsigned short*)Cout)[(size_t)(row0 + r) * N + col] = f2b(v);
        } else {
          const float xr = xref[(size_t)(row0 + r) * N + col];
          const float df = v - xr;
          lsum += (double)df * (double)df;
          ((float*)Cout)[(size_t)(row0 + r) * N + col] = v;
        }
      }
    }
  }
  if (EPI == 1) {
#pragma unroll
    for (int o = 32; o; o >>= 1) lsum += __shfl_down(lsum, o);
    if (l == 0) atomicAdd(accums + 1, lsum);
  }
}

__global__ __launch_bounds__(256, 2) void dec1_k(const unsigned short* A,
                                                 const unsigned short* Bt,
                                                 const float* bias,
                                                 unsigned short* C, int M,
                                                 int N, int K) {
  mgemm_body<0>(A, Bt, bias, C, M, N, K, nullptr, nullptr);
}
__global__ __launch_bounds__(256, 2) void dec2_k(const unsigned short* A,
                                                 const unsigned short* Bt,
                                                 const float* bias,
                                                 unsigned short* C, int M,
                                                 int N, int K) {
  mgemm_body<0>(A, Bt, bias, C, M, N, K, nullptr, nullptr);
}
__global__ __launch_bounds__(256, 2) void dec3_k(const unsigned short* A,
                                                 const unsigned short* Bt,
                                                 const float* bias, float* C,
                                                 int M, int N, int K,
                                                 const float* xref,
                                                 double* accums) {
  mgemm_body<1>(A, Bt, bias, C, M, N, K, xref, accums);
}

// transpose-cast fp32 [K][N] -> bf16 [N][K]
__global__ void castT_k(const float* __restrict__ W,
                        unsigned short* __restrict__ out, int K, int N) {
  __shared__ float t[32][33];
  const int tx = threadIdx.x & 31, ty4 = threadIdx.x >> 5;
  const int nb = blockIdx.x << 5, kb = blockIdx.y << 5;
#pragma unroll
  for (int r = 0; r < 4; ++r) {
    const int k = (ty4 << 2) + r;
    t[k][tx] = W[(size_t)(kb + k) * N + nb + tx];
  }
  __syncthreads();
#pragma unroll
  for (int r = 0; r < 4; ++r) {
    const int n = (ty4 << 2) + r;
    out[(size_t)(nb + n) * K + kb + tx] = f2b(t[tx][n]);
  }
}

__global__ void rowsumsq(const float* __restrict__ v, float* __restrict__ out,
                         int rows) {
  const int w = (int)((blockIdx.x * blockDim.x + threadIdx.x) >> 6);
  const int lane = threadIdx.x & 63;
  if (w >= rows) return;
  const float4 x = *(const float4*)(v + (size_t)w * 256 + (lane << 2));
  float s = ((x.x * x.x + x.y * x.y) + x.z * x.z) + x.w * x.w;
#pragma unroll
  for (int o = 32; o; o >>= 1) s += __shfl_down(s, o);
  if (lane == 0) out[w] = s;
}

__global__ void finalize_vq(const unsigned long long* __restrict__ keys,
                            const float* __restrict__ z,
                            const float* __restrict__ cb,
                            unsigned short* __restrict__ qst_bf,
                            float* __restrict__ tok, int* __restrict__ counts,
                            double* __restrict__ accums) {
  const int row = (int)((blockIdx.x * blockDim.x + threadIdx.x) >> 6);
  const int lane = threadIdx.x & 63;
  if (row >= B_N) return;
  const int idx = (int)(keys[row] & 0xffffffffull);
  const float4 zv = *(const float4*)(z + (size_t)row * 256 + (lane << 2));
  const float4 evv = *(const float4*)(cb + (size_t)idx * 256 + (lane << 2));
  float4 q;
  double s = 0.0;
  float d;
  d = evv.x - zv.x; q.x = zv.x + d; s += (double)d * (double)d;
  d = evv.y - zv.y; q.y = zv.y + d; s += (double)d * (double)d;
  d = evv.z - zv.z; q.z = zv.z + d; s += (double)d * (double)d;
  d = evv.w - zv.w; q.w = zv.w + d; s += (double)d * (double)d;
  ushort4 qb;
  qb.x = f2b(q.x); qb.y = f2b(q.y); qb.z = f2b(q.z); qb.w = f2b(q.w);
  *(ushort4*)(qst_bf + (size_t)row * 256 + (lane << 2)) = qb;
#pragma unroll
  for (int o = 32; o; o >>= 1) s += __shfl_down(s, o);
  if (lane == 0) {
    atomicAdd(accums + 0, s);
    tok[row] = (float)idx;
    atomicAdd(counts + idx, 1);
  }
}

__global__ void finalize_scalars(const int* __restrict__ counts,
                                 const double* __restrict__ accums,
                                 float* __restrict__ outs) {
  __shared__ double red[256];
  double h = 0.0;
  for (int k = threadIdx.x; k < K_CB; k += 256) {
    const float p = (float)counts[k] * (1.0f / 8192.0f);
    const float t = p * logf(p + 1e-10f);
    h += (double)t;
  }
  red[threadIdx.x] = h;
  __syncthreads();
  for (int s = 128; s; s >>= 1) {
    if ((int)threadIdx.x < s) red[threadIdx.x] += red[threadIdx.x + s];
    __syncthreads();
  }
  if (threadIdx.x == 0) {
    const float perp = expf((float)(-red[0]));
    const float m1 = (float)(accums[0] * (1.0 / ((double)B_N * (double)D_LAT)));
    const float vq = m1 + 0.25f * m1;
    const float rl = (float)(accums[1] * (1.0 / ((double)B_N * (double)D_IN)));
    outs[0] = vq;
    outs[1] = rl;
    outs[2] = vq + rl;
    outs[3] = perp;
  }
}

extern "C" void kernel_launch(void* const* d_in, const int* in_sizes, int n_in,
                              void* d_out, int out_size, void* d_ws,
                              size_t ws_size, hipStream_t stream) {
  (void)in_sizes; (void)n_in; (void)out_size;
  const float* x   = (const float*)d_in[0];
  const float* eW1 = (const float*)d_in[1];
  const float* eb1 = (const float*)d_in[2];
  const float* eW2 = (const float*)d_in[3];
  const float* eb2 = (const float*)d_in[4];
  const float* eW3 = (const float*)d_in[5];
  const float* eb3 = (const float*)d_in[6];
  const float* cb  = (const float*)d_in[7];
  const float* dW1 = (const float*)d_in[8];
  const float* db1 = (const float*)d_in[9];
  const float* dW2 = (const float*)d_in[10];
  const float* db2 = (const float*)d_in[11];
  const float* dW3 = (const float*)d_in[12];
  const float* db3 = (const float*)d_in[13];
  float* out = (float*)d_out;

  char* ws = (char*)d_ws;
  const size_t OFF_Z      = 0;
  const size_t OFF_EEV    = OFF_Z + (size_t)B_N * D_LAT * 4;
  const size_t OFF_ZZV    = OFF_EEV + (size_t)K_CB * 4;
  const size_t OFF_KEYS   = OFF_ZZV + (size_t)B_N * 4;
  const size_t OFF_COUNTS = OFF_KEYS + (size_t)B_N * 8;
  const size_t OFF_ACC    = OFF_COUNTS + (size_t)K_CB * 4;
  const size_t OFF_QB     = OFF_ACC + 256;
  const size_t OFF_K2     = OFF_QB + (size_t)B_N * D_LAT * 2;
  const size_t OFF_H      = OFF_K2 + (size_t)B_N * VQ_NB * 8;

  float* z    = (float*)(ws + OFF_Z);
  float* eev  = (float*)(ws + OFF_EEV);
  float* zzv  = (float*)(ws + OFF_ZZV);
  unsigned long long* keys = (unsigned long long*)(ws + OFF_KEYS);
  int* counts = (int*)(ws + OFF_COUNTS);
  double* accums = (double*)(ws + OFF_ACC);
  unsigned short* qst_bf = (unsigned short*)(ws + OFF_QB);
  unsigned long long* keys2 = (unsigned long long*)(ws + OFF_K2);

  const size_t SZ_XT = (size_t)D_IN * B_N * 4;  // 32MB
  int cA = 0;
  for (int c = 8192; c >= 1024; c >>= 1)
    if (OFF_H + SZ_XT + 2ull * c * D_HID * 4 <= ws_size) { cA = c; break; }

  int c_enc = 256;
  for (int c = 8192; c >= 256; c >>= 1)
    if (OFF_H + 2ull * c * D_HID * 4 <= ws_size) { c_enc = c; break; }

  const size_t SZ_WB1 = (size_t)D_HID * D_LAT * 2;
  const size_t SZ_WB2 = (size_t)D_HID * D_HID * 2;
  const size_t SZ_WB3 = (size_t)D_IN * D_HID * 2;
  const size_t OFF_DECH = OFF_H + SZ_WB1 + SZ_WB2 + SZ_WB3;
  int c_dec = 128;
  for (int c = 8192; c >= 128; c >>= 1)
    if (OFF_DECH + 2ull * c * D_HID * 2 <= ws_size) { c_dec = c; break; }
  unsigned short* wB1 = (unsigned short*)(ws + OFF_H);
  unsigned short* wB2 = (unsigned short*)(ws + OFF_H + SZ_WB1);
  unsigned short* wB3 = (unsigned short*)(ws + OFF_H + SZ_WB1 + SZ_WB2);
  unsigned short* hbfA = (unsigned short*)(ws + OFF_DECH);
  unsigned short* hbfB = hbfA + (size_t)c_dec * D_HID;

  float* tok_out = out + (size_t)B_N * D_IN;
  float* scal_out = tok_out + B_N;

  hipMemsetAsync(counts, 0, (size_t)K_CB * 4, stream);
  hipMemsetAsync(accums, 0, 2 * sizeof(double), stream);

  rowsumsq<<<(K_CB * 64) / 256, 256, 0, stream>>>(cb, eev, K_CB);

  float* zT;
  float* cbT;
  if (cA >= 4096) {
    // ---- encoder, A^T-chained & chunked (bit-identical chain) ----
    float* xT = (float*)(ws + OFF_H);          // [1024][8192] 32MB
    float* hAT = xT + (size_t)D_IN * B_N;      // [4096][cA]
    float* hBT = hAT + (size_t)D_HID * cA;     // [4096][cA]
    float* P3 = hAT;                           // split-K partials (hAT dead)
    transF_k<<<dim3(D_IN / 32, B_N / 32), 256, 0, stream>>>(x, xT, B_N, D_IN);
    for (int c0 = 0; c0 < B_N; c0 += cA) {
      enc1_k<<<dim3(D_HID / 128, cA / 256), 256, 0, stream>>>(
          xT, eW1, eb1, hAT, B_N, c0, cA, D_HID, D_IN);
      enc2_k<<<dim3(D_HID / 128, cA / 256), 256, 0, stream>>>(
          hAT, eW2, eb2, hBT, cA, 0, cA, D_HID, D_HID);
      enc3_part_k<true><<<dim3(D_LAT / 128, cA / 128, 8), 256, 0, stream>>>(
          hBT, eW3, P3, cA, D_HID, cA);
      enc3_comb_k<<<(cA * (D_LAT / 4) + 255) / 256, 256, 0, stream>>>(
          P3, eb3, z + (size_t)c0 * D_LAT, cA);
    }
    zT = xT;                                    // 8MB (xT dead)
    cbT = xT + (size_t)D_LAT * B_N;             // 16MB
  } else {
    float* hA = (float*)(ws + OFF_H);
    float* hB = hA + (size_t)c_enc * D_HID;
    float* P3 = hA;
    for (int c0 = 0; c0 < B_N; c0 += c_enc) {
      const dim3 gH(D_HID / 128, c_enc / 128);
      enc_small_k<<<gH, 256, 0, stream>>>(x + (size_t)c0 * D_IN, eW1, eb1, hA,
                                          c_enc, D_HID, D_IN);
      enc_small_k<<<gH, 256, 0, stream>>>(hA, eW2, eb2, hB, c_enc, D_HID,
                                          D_HID);
      enc3_part_k<false><<<dim3(D_LAT / 128, c_enc / 128, 8), 256, 0, stream>>>(
          hB, eW3, P3, c_enc, D_HID, 0);
      enc3_comb_k<<<(c_enc * (D_LAT / 4) + 255) / 256, 256, 0, stream>>>(
          P3, eb3, z + (size_t)c0 * D_LAT, c_enc);
    }
    zT = hA;
    cbT = hB;
  }

  // ---- VQ prep: z^T, cb^T (into now-dead encoder buffers) ----
  transF_k<<<dim3(D_LAT / 32, B_N / 32), 256, 0, stream>>>(z, zT, B_N, D_LAT);
  transF_k<<<dim3(D_LAT / 32, K_CB / 32), 256, 0, stream>>>(cb, cbT, K_CB,
                                                            D_LAT);
  rowsumsq<<<(B_N * 64) / 256, 256, 0, stream>>>(z, zzv, B_N);

  // ---- VQ (atomic-free 2-stage) ----
  vq_k256<<<dim3(VQ_NB, B_N / 256), 256, 0, stream>>>(zT, cbT, zzv, eev, keys2);
  vq_red_k<<<(B_N * 64) / 256, 256, 0, stream>>>(keys2, keys);
  finalize_vq<<<(B_N * 64) / 256, 256, 0, stream>>>(keys, z, cb, qst_bf,
                                                    tok_out, counts, accums);

  // ---- decoder weight transpose-casts ----
  castT_k<<<dim3(D_HID / 32, D_LAT / 32), 256, 0, stream>>>(dW1, wB1, D_LAT, D_HID);
  castT_k<<<dim3(D_HID / 32, D_HID / 32), 256, 0, stream>>>(dW2, wB2, D_HID, D_HID);
  castT_k<<<dim3(D_IN / 32, D_HID / 32), 256, 0, stream>>>(dW3, wB3, D_HID, D_IN);

  // ---- decoder (bf16 MFMA) ----
  for (int c0 = 0; c0 < B_N; c0 += c_dec) {
    const dim3 gH(D_HID / 128, c_dec / 128);
    dec1_k<<<gH, 256, 0, stream>>>(qst_bf + (size_t)c0 * D_LAT, wB1, db1, hbfA,
                                   c_dec, D_HID, D_LAT);
    dec2_k<<<gH, 256, 0, stream>>>(hbfA, wB2, db2, hbfB, c_dec, D_HID, D_HID);
    dec3_k<<<dim3(D_IN / 128, c_dec / 128), 256, 0, stream>>>(
        hbfB, wB3, db3, out + (size_t)c0 * D_IN, c_dec, D_IN, D_HID,
        x + (size_t)c0 * D_IN, accums);
  }

  finalize_scalars<<<1, 256, 0, stream>>>(counts, accums, scal_out);
}

// Round 14
// 5252.094 us; speedup vs baseline: 1.0505x; 1.0037x over previous
//
#include <hip/hip_runtime.h>
#include <stdint.h>

#define B_N 8192
#define D_IN 1024
#define D_HID 4096
#define D_LAT 256
#define K_CB 16384
#define VQ_NB (K_CB / 128)

typedef __attribute__((ext_vector_type(8))) short bf16x8;
typedef __attribute__((ext_vector_type(4))) float f32x4;
typedef __attribute__((ext_vector_type(2))) float f32x2;

__device__ __forceinline__ unsigned short f2b(float v) {
  unsigned u = __float_as_uint(v);
  u += 0x7fffu + ((u >> 16) & 1u);  // RNE (finite values)
  return (unsigned short)(u >> 16);
}

// bijective XCD swizzle; requires gridDim.x*gridDim.y % 8 == 0
#define XCD_SWIZZLE(bx, by)                                   \
  {                                                           \
    const int gx_ = gridDim.x, n_ = gx_ * gridDim.y;          \
    const int wg_ = (by)*gx_ + (bx);                          \
    const int q_ = n_ >> 3;                                   \
    const int s_ = (wg_ & 7) * q_ + (wg_ >> 3);               \
    (bx) = s_ % gx_;                                          \
    (by) = s_ / gx_;                                          \
  }

// ---------- fp32 transpose [R][C] -> [C][R] ------------------------------
__global__ void transF_k(const float* __restrict__ in, float* __restrict__ out,
                         int R, int C) {
  __shared__ float t[32][33];
  const int tx = threadIdx.x & 31, ty4 = threadIdx.x >> 5;
  const int rb = blockIdx.y << 5, cb_ = blockIdx.x << 5;
#pragma unroll
  for (int r = 0; r < 4; ++r) {
    const int lr = (ty4 << 2) + r;
    t[lr][tx] = in[(size_t)(rb + lr) * C + cb_ + tx];
  }
  __syncthreads();
#pragma unroll
  for (int r = 0; r < 4; ++r) {
    const int lr = (ty4 << 2) + r;
    out[(size_t)(cb_ + lr) * R + rb + tx] = t[tx][lr];
  }
}

// ---------- 256x128 fp32 GEMM + bias + ReLU, A^T in, C^T out, dbuf, pk ---
// Packed f32x2 FMA over j-pairs: per-element IEEE fma chain over k is
// IDENTICAL to rounds 4-13 (v_pk_fma_f32 halves == v_fma_f32) -> bit-stable.
__device__ __forceinline__ void enc_bigT_body(
    const float* __restrict__ AT_, const float* __restrict__ Bm,
    const float* __restrict__ bias, float* __restrict__ CT, int Ms_in,
    int mbase, int Mc, int N, int K) {
  __shared__ float As[2][16 * 256];
  __shared__ float Bs[2][16 * 128];
  const int tid = threadIdx.x;
  const int w = tid >> 6;
  const int tx = tid & 15, ty = tid >> 4;
  int bx = blockIdx.x, by = blockIdx.y;
  XCD_SWIZZLE(bx, by)
  const int m0 = by << 8, n0 = bx << 7;

  f32x2 acc2[16][4];
#pragma unroll
  for (int i = 0; i < 16; ++i)
#pragma unroll
    for (int q = 0; q < 4; ++q) acc2[i][q] = (f32x2)0.0f;

  auto stage = [&](int buf, int k0) {
#pragma unroll
    for (int r = 0; r < 4; ++r) {  // A^T tile: 16k x 256m, linear [k][m]
      const int f = tid + (r << 8);
      const float* gp =
          AT_ + (size_t)(k0 + (f >> 6)) * Ms_in + mbase + m0 + ((f & 63) << 2);
      __builtin_amdgcn_global_load_lds(
          (const unsigned int*)gp,
          (unsigned int*)&As[buf][(r << 10) + (w << 8)], 16, 0, 0);
    }
#pragma unroll
    for (int r = 0; r < 2; ++r) {  // B tile: 16k x 128n, linear [k][n]
      const int f = tid + (r << 8);
      const float* gp = Bm + (size_t)(k0 + (f >> 5)) * N + n0 + ((f & 31) << 2);
      __builtin_amdgcn_global_load_lds(
          (const unsigned int*)gp,
          (unsigned int*)&Bs[buf][(r << 10) + (w << 8)], 16, 0, 0);
    }
  };

  stage(0, 0);
  const int nb = K >> 4;
  for (int t = 0; t < nb; ++t) {
    __syncthreads();
    if (t + 1 < nb) stage((t + 1) & 1, (t + 1) << 4);
    const int cur = t & 1;
#pragma unroll
    for (int kk = 0; kk < 16; ++kk) {
      float a[16];
      f32x2 b2[4];
#pragma unroll
      for (int q = 0; q < 4; ++q)
        *(float4*)(a + (q << 2)) =
            *(const float4*)(&As[cur][kk * 256 + (q << 6) + (ty << 2)]);
      {
        const float4 blo = *(const float4*)(&Bs[cur][kk * 128 + (tx << 2)]);
        const float4 bhi =
            *(const float4*)(&Bs[cur][kk * 128 + 64 + (tx << 2)]);
        b2[0] = f32x2{blo.x, blo.y};
        b2[1] = f32x2{blo.z, blo.w};
        b2[2] = f32x2{bhi.x, bhi.y};
        b2[3] = f32x2{bhi.z, bhi.w};
      }
#pragma unroll
      for (int i = 0; i < 16; ++i) {
        const f32x2 a2 = {a[i], a[i]};
#pragma unroll
        for (int q = 0; q < 4; ++q)
          acc2[i][q] = __builtin_elementwise_fma(a2, b2[q], acc2[i][q]);
      }
    }
  }

  float bb[8];
  *(float4*)(bb) = *(const float4*)(bias + n0 + (tx << 2));
  *(float4*)(bb + 4) = *(const float4*)(bias + n0 + 64 + (tx << 2));
#pragma unroll
  for (int j = 0; j < 8; ++j) {
    const int col = n0 + ((j >> 2) << 6) + (tx << 2) + (j & 3);
#pragma unroll
    for (int q = 0; q < 4; ++q) {
      float vq4[4];
#pragma unroll
      for (int r = 0; r < 4; ++r)
        vq4[r] = fmaxf(acc2[(q << 2) + r][j >> 1][j & 1] + bb[j], 0.0f);
      *(float4*)(CT + (size_t)col * Mc + m0 + (q << 6) + (ty << 2)) =
          *(float4*)(vq4);
    }
  }
}

__global__ __launch_bounds__(256, 2) void enc1_k(const float* AT_,
                                                 const float* B,
                                                 const float* bias, float* CT,
                                                 int Ms_in, int mbase, int Mc,
                                                 int N, int K) {
  enc_bigT_body(AT_, B, bias, CT, Ms_in, mbase, Mc, N, K);
}
__global__ __launch_bounds__(256, 2) void enc2_k(const float* AT_,
                                                 const float* B,
                                                 const float* bias, float* CT,
                                                 int Ms_in, int mbase, int Mc,
                                                 int N, int K) {
  enc_bigT_body(AT_, B, bias, CT, Ms_in, mbase, Mc, N, K);
}

// ---------- 128^2 fp32 GEMM + ReLU (fallback, row-major) ----------------
__global__ __launch_bounds__(256, 2) void enc_small_k(
    const float* __restrict__ A, const float* __restrict__ Bm,
    const float* __restrict__ bias, float* __restrict__ C, int M, int N,
    int K) {
  __shared__ float As[16][128];
  __shared__ float Bs[16][128];
  const int tid = threadIdx.x;
  const int tx = tid & 15, ty = tid >> 4;
  const int m0 = blockIdx.y << 7, n0 = blockIdx.x << 7;
  float acc[8][8];
#pragma unroll
  for (int i = 0; i < 8; ++i)
#pragma unroll
    for (int j = 0; j < 8; ++j) acc[i][j] = 0.0f;
  for (int k0 = 0; k0 < K; k0 += 16) {
#pragma unroll
    for (int r = 0; r < 2; ++r) {
      const int f = tid + (r << 8);
      const int m = f >> 2, kq = (f & 3) << 2;
      const float4 v = *(const float4*)(A + (size_t)(m0 + m) * K + k0 + kq);
      As[kq + 0][m] = v.x; As[kq + 1][m] = v.y;
      As[kq + 2][m] = v.z; As[kq + 3][m] = v.w;
    }
#pragma unroll
    for (int r = 0; r < 2; ++r) {
      const int f = tid + (r << 8);
      const int k = f >> 5, nq = (f & 31) << 2;
      *(float4*)(&Bs[k][nq]) =
          *(const float4*)(Bm + (size_t)(k0 + k) * N + n0 + nq);
    }
    __syncthreads();
#pragma unroll
    for (int kk = 0; kk < 16; ++kk) {
      float a[8], b[8];
      *(float4*)(a) = *(const float4*)(&As[kk][ty << 2]);
      *(float4*)(a + 4) = *(const float4*)(&As[kk][64 + (ty << 2)]);
      *(float4*)(b) = *(const float4*)(&Bs[kk][tx << 2]);
      *(float4*)(b + 4) = *(const float4*)(&Bs[kk][64 + (tx << 2)]);
#pragma unroll
      for (int i = 0; i < 8; ++i)
#pragma unroll
        for (int j = 0; j < 8; ++j) acc[i][j] = fmaf(a[i], b[j], acc[i][j]);
    }
    __syncthreads();
  }
  float bb[8];
  *(float4*)(bb) = *(const float4*)(bias + n0 + (tx << 2));
  *(float4*)(bb + 4) = *(const float4*)(bias + n0 + 64 + (tx << 2));
#pragma unroll
  for (int i = 0; i < 8; ++i) {
    const int row = m0 + ((i < 4) ? (ty << 2) + i : 64 + (ty << 2) + i - 4);
    float vrow[8];
#pragma unroll
    for (int j = 0; j < 8; ++j) vrow[j] = fmaxf(acc[i][j] + bb[j], 0.0f);
    *(float4*)(C + (size_t)row * N + n0 + (tx << 2)) = *(float4*)(vrow);
    *(float4*)(C + (size_t)row * N + n0 + 64 + (tx << 2)) = *(float4*)(vrow + 4);
  }
}

// ---------- eW3 split-K=8 partial; AT: A^T [K][Mstr], pk inner -----------
template <bool AT>
__global__ __launch_bounds__(256, 2) void enc3_part_k(
    const float* __restrict__ A, const float* __restrict__ B,
    float* __restrict__ P, int M, int K, int Mstr) {
  __shared__ float As[16 * 128];
  __shared__ float Bs[16 * 128];
  const int tid = threadIdx.x;
  const int w = tid >> 6;
  const int tx = tid & 15, ty = tid >> 4;
  const int m0 = blockIdx.y << 7, n0 = blockIdx.x << 7;
  const int s = blockIdx.z;
  const int kbeg = s * (K >> 3), kend = kbeg + (K >> 3);
  f32x2 acc2[8][4];
#pragma unroll
  for (int i = 0; i < 8; ++i)
#pragma unroll
    for (int q = 0; q < 4; ++q) acc2[i][q] = (f32x2)0.0f;
  for (int k0 = kbeg; k0 < kend; k0 += 16) {
    if (AT) {
#pragma unroll
      for (int r = 0; r < 2; ++r) {  // 16k x 128m, linear [k][m]
        const int f = tid + (r << 8);
        const float* gp =
            A + (size_t)(k0 + (f >> 5)) * Mstr + m0 + ((f & 31) << 2);
        __builtin_amdgcn_global_load_lds(
            (const unsigned int*)gp, (unsigned int*)&As[(r << 10) + (w << 8)],
            16, 0, 0);
      }
    } else {
#pragma unroll
      for (int r = 0; r < 2; ++r) {
        const int f = tid + (r << 8);
        const int m = f >> 2, kq = (f & 3) << 2;
        const float4 v = *(const float4*)(A + (size_t)(m0 + m) * K + k0 + kq);
        As[(kq + 0) * 128 + m] = v.x; As[(kq + 1) * 128 + m] = v.y;
        As[(kq + 2) * 128 + m] = v.z; As[(kq + 3) * 128 + m] = v.w;
      }
    }
#pragma unroll
    for (int r = 0; r < 2; ++r) {  // B [K][256] rows: lane-linear
      const int f = tid + (r << 8);
      const float* gp = B + (size_t)(k0 + (f >> 5)) * D_LAT + n0 + ((f & 31) << 2);
      __builtin_amdgcn_global_load_lds((const unsigned int*)gp,
                                       (unsigned int*)&Bs[(r << 10) + (w << 8)],
                                       16, 0, 0);
    }
    __syncthreads();
#pragma unroll
    for (int kk = 0; kk < 16; ++kk) {
      float a[8];
      f32x2 b2[4];
      *(float4*)(a) = *(const float4*)(&As[kk * 128 + (ty << 2)]);
      *(float4*)(a + 4) = *(const float4*)(&As[kk * 128 + 64 + (ty << 2)]);
      {
        const float4 blo = *(const float4*)(&Bs[kk * 128 + (tx << 2)]);
        const float4 bhi = *(const float4*)(&Bs[kk * 128 + 64 + (tx << 2)]);
        b2[0] = f32x2{blo.x, blo.y};
        b2[1] = f32x2{blo.z, blo.w};
        b2[2] = f32x2{bhi.x, bhi.y};
        b2[3] = f32x2{bhi.z, bhi.w};
      }
#pragma unroll
      for (int i = 0; i < 8; ++i) {
        const f32x2 a2 = {a[i], a[i]};
#pragma unroll
        for (int q = 0; q < 4; ++q)
          acc2[i][q] = __builtin_elementwise_fma(a2, b2[q], acc2[i][q]);
      }
    }
    __syncthreads();
  }
  float* Ps = P + (size_t)s * M * D_LAT;
#pragma unroll
  for (int i = 0; i < 8; ++i) {
    const int row = m0 + ((i < 4) ? (ty << 2) + i : 64 + (ty << 2) + i - 4);
    float vr[8];
#pragma unroll
    for (int j = 0; j < 8; ++j) vr[j] = acc2[i][j >> 1][j & 1];
    *(float4*)(Ps + (size_t)row * D_LAT + n0 + (tx << 2)) = *(float4*)(vr);
    *(float4*)(Ps + (size_t)row * D_LAT + n0 + 64 + (tx << 2)) = *(float4*)(vr + 4);
  }
}

// combine 8 partials + bias, tanh -> z
__global__ void enc3_comb_k(const float* __restrict__ P,
                            const float* __restrict__ bias,
                            float* __restrict__ z, int M) {
  const size_t i4 = (size_t)blockIdx.x * blockDim.x + threadIdx.x;
  const size_t tot = (size_t)M * (D_LAT / 4);
  if (i4 >= tot) return;
  const size_t sstr = (size_t)M * (D_LAT / 4);
  const float4* Pv = (const float4*)P;
  float sx = 0.f, sy = 0.f, sz = 0.f, sw = 0.f;
#pragma unroll
  for (int s = 0; s < 8; ++s) {
    const float4 v = Pv[i4 + (size_t)s * sstr];
    sx += v.x; sy += v.y; sz += v.z; sw += v.w;
  }
  const int col = (int)((i4 << 2) & (D_LAT - 1));
  const float4 bb = *(const float4*)(bias + col);
  float4 o;
  o.x = tanhf(sx + bb.x);
  o.y = tanhf(sy + bb.y);
  o.z = tanhf(sz + bb.z);
  o.w = tanhf(sw + bb.w);
  ((float4*)z)[i4] = o;
}

// ---------- VQ distance+argmin, 256x128, zT/cbT inputs, dbuf, pk ---------
__global__ __launch_bounds__(256, 2) void vq_k256(
    const float* __restrict__ zT, const float* __restrict__ cbT,
    const float* __restrict__ zz, const float* __restrict__ ee,
    unsigned long long* __restrict__ keys2) {
  __shared__ float As[2][16 * 256];
  __shared__ float Bs[2][16 * 128];
  const int tid = threadIdx.x;
  const int w = tid >> 6;
  const int tx = tid & 15, ty = tid >> 4;
  int bx = blockIdx.x, by = blockIdx.y;
  XCD_SWIZZLE(bx, by)
  const int m0 = by << 8, n0 = bx << 7;

  f32x2 acc2[16][4];
#pragma unroll
  for (int i = 0; i < 16; ++i)
#pragma unroll
    for (int q = 0; q < 4; ++q) acc2[i][q] = (f32x2)0.0f;

  auto stage = [&](int buf, int k0) {
#pragma unroll
    for (int r = 0; r < 4; ++r) {  // z^T [256][B_N]: 16k x 256m
      const int f = tid + (r << 8);
      const float* gp = zT + (size_t)(k0 + (f >> 6)) * B_N + m0 + ((f & 63) << 2);
      __builtin_amdgcn_global_load_lds(
          (const unsigned int*)gp,
          (unsigned int*)&As[buf][(r << 10) + (w << 8)], 16, 0, 0);
    }
#pragma unroll
    for (int r = 0; r < 2; ++r) {  // cb^T [256][K_CB]: 16k x 128n
      const int f = tid + (r << 8);
      const float* gp = cbT + (size_t)(k0 + (f >> 5)) * K_CB + n0 + ((f & 31) << 2);
      __builtin_amdgcn_global_load_lds(
          (const unsigned int*)gp,
          (unsigned int*)&Bs[buf][(r << 10) + (w << 8)], 16, 0, 0);
    }
  };

  stage(0, 0);
  const int nb = D_LAT >> 4;
  for (int t = 0; t < nb; ++t) {
    __syncthreads();
    if (t + 1 < nb) stage((t + 1) & 1, (t + 1) << 4);
    const int cur = t & 1;
#pragma unroll
    for (int kk = 0; kk < 16; ++kk) {
      float a[16];
      f32x2 b2[4];
#pragma unroll
      for (int q = 0; q < 4; ++q)
        *(float4*)(a + (q << 2)) =
            *(const float4*)(&As[cur][kk * 256 + (q << 6) + (ty << 2)]);
      {
        const float4 blo = *(const float4*)(&Bs[cur][kk * 128 + (tx << 2)]);
        const float4 bhi =
            *(const float4*)(&Bs[cur][kk * 128 + 64 + (tx << 2)]);
        b2[0] = f32x2{blo.x, blo.y};
        b2[1] = f32x2{blo.z, blo.w};
        b2[2] = f32x2{bhi.x, bhi.y};
        b2[3] = f32x2{bhi.z, bhi.w};
      }
#pragma unroll
      for (int i = 0; i < 16; ++i) {
        const f32x2 a2 = {a[i], a[i]};
#pragma unroll
        for (int q = 0; q < 4; ++q)
          acc2[i][q] = __builtin_elementwise_fma(a2, b2[q], acc2[i][q]);
      }
    }
  }

  // EXACT reference fp32 expression: d = fl(fl(zz+ee) - 2*dot); first-index
  // tie-break preserved by packed u64 (ordered bits << 32 | col) min.
  float zr[16];
#pragma unroll
  for (int i = 0; i < 16; ++i)
    zr[i] = zz[m0 + ((i >> 2) << 6) + (ty << 2) + (i & 3)];
  float ev[8];
  *(float4*)(ev) = *(const float4*)(ee + n0 + (tx << 2));
  *(float4*)(ev + 4) = *(const float4*)(ee + n0 + 64 + (tx << 2));
#pragma unroll
  for (int i = 0; i < 16; ++i) {
    unsigned long long bk = ~0ull;
#pragma unroll
    for (int j = 0; j < 8; ++j) {
      const int col = n0 + ((j >> 2) << 6) + (tx << 2) + (j & 3);
      const float t = zr[i] + ev[j];
      const float d = t - 2.0f * acc2[i][j >> 1][j & 1];
      unsigned u = __float_as_uint(d);
      u = (u & 0x80000000u) ? ~u : (u | 0x80000000u);
      const unsigned long long key = ((unsigned long long)u << 32) | (unsigned)col;
      bk = key < bk ? key : bk;
    }
#pragma unroll
    for (int s = 1; s <= 8; s <<= 1) {
      const unsigned long long o = __shfl_xor(bk, s);
      if (o < bk) bk = o;
    }
    if (tx == 0) {
      const int row = m0 + ((i >> 2) << 6) + (ty << 2) + (i & 3);
      keys2[(size_t)row * VQ_NB + bx] = bk;
    }
  }
}

__global__ void vq_red_k(const unsigned long long* __restrict__ keys2,
                         unsigned long long* __restrict__ keys) {
  const int row = (int)((blockIdx.x * blockDim.x + threadIdx.x) >> 6);
  const int lane = threadIdx.x & 63;
  if (row >= B_N) return;
  unsigned long long a = keys2[(size_t)row * VQ_NB + lane];
  const unsigned long long b = keys2[(size_t)row * VQ_NB + 64 + lane];
  a = b < a ? b : a;
#pragma unroll
  for (int s = 32; s; s >>= 1) {
    const unsigned long long o = __shfl_xor(a, s);
    a = o < a ? o : a;
  }
  if (lane == 0) keys[row] = a;
}

// ---------------- bf16 MFMA GEMM (decoder), m97 structure ----------------
template <int EPI>
__device__ __forceinline__ void mgemm_body(
    const unsigned short* __restrict__ A, const unsigned short* __restrict__ Bt,
    const float* __restrict__ bias, void* __restrict__ Cout, int M, int N,
    int K, const float* __restrict__ xref, double* __restrict__ accums) {
  __shared__ __align__(16) unsigned short As[4096];
  __shared__ __align__(16) unsigned short Bs[4096];
  const int tid = threadIdx.x;
  const int w = tid >> 6, l = tid & 63;
  const int wr = w >> 1, wc = w & 1;
  const int g = l >> 4, tx = l & 15;
  int bx = blockIdx.x, by = blockIdx.y;
  XCD_SWIZZLE(bx, by)
  const int m0 = by << 7, n0 = bx << 7;

  f32x4 acc[4][4];
#pragma unroll
  for (int i = 0; i < 4; ++i)
#pragma unroll
    for (int j = 0; j < 4; ++j) acc[i][j] = (f32x4)0.0f;

  for (int k0 = 0; k0 < K; k0 += 32) {
#pragma unroll
    for (int c = 0; c < 2; ++c) {
      const int f = tid + (c << 8);
      const unsigned short* ga =
          A + (size_t)(m0 + (f >> 2)) * K + k0 + ((f & 3) << 3);
      __builtin_amdgcn_global_load_lds((const unsigned int*)ga,
                                       (unsigned int*)&As[(c << 11) + (w << 9)],
                                       16, 0, 0);
      const unsigned short* gb =
          Bt + (size_t)(n0 + (f >> 2)) * K + k0 + ((f & 3) << 3);
      __builtin_amdgcn_global_load_lds((const unsigned int*)gb,
                                       (unsigned int*)&Bs[(c << 11) + (w << 9)],
                                       16, 0, 0);
    }
    __syncthreads();
    bf16x8 af[4], bfv[4];
#pragma unroll
    for (int f = 0; f < 4; ++f) {
      af[f] = *(const bf16x8*)&As[((wr << 6) + (f << 4) + tx) * 32 + (g << 3)];
      bfv[f] = *(const bf16x8*)&Bs[((wc << 6) + (f << 4) + tx) * 32 + (g << 3)];
    }
#pragma unroll
    for (int fm = 0; fm < 4; ++fm)
#pragma unroll
      for (int fn = 0; fn < 4; ++fn)
        acc[fm][fn] = __builtin_amdgcn_mfma_f32_16x16x32_bf16(
            af[fm], bfv[fn], acc[fm][fn], 0, 0, 0);
    __syncthreads();
  }

  double lsum = 0.0;
#pragma unroll
  for (int fm = 0; fm < 4; ++fm) {
    const int row0 = m0 + (wr << 6) + (fm << 4) + (g << 2);
#pragma unroll
    for (int fn = 0; fn < 4; ++fn) {
      const int col = n0 + (wc << 6) + (fn << 4) + tx;
      const float bb = bias[col];
#pragma unroll
      for (int r = 0; r < 4; ++r) {
        float v = acc[fm][fn][r] + bb;
        if (EPI == 0) {
          v = fmaxf(v, 0.0f);
          ((unsigned short*)Cout)[(size_t)(row0 + r) * N + col] = f2b(v);
        } else {
          const float xr = xref[(size_t)(row0 + r) * N + col];
          const float df = v - xr;
          lsum += (double)df * (double)df;
          ((float*)Cout)[(size_t)(row0 + r) * N + col] = v;
        }
      }
    }
  }
  if (EPI == 1) {
#pragma unroll
    for (int o = 32; o; o >>= 1) lsum += __shfl_down(lsum, o);
    if (l == 0) atomicAdd(accums + 1, lsum);
  }
}

__global__ __launch_bounds__(256, 2) void dec1_k(const unsigned short* A,
                                                 const unsigned short* Bt,
                                                 const float* bias,
                                                 unsigned short* C, int M,
                                                 int N, int K) {
  mgemm_body<0>(A, Bt, bias, C, M, N, K, nullptr, nullptr);
}
__global__ __launch_bounds__(256, 2) void dec2_k(const unsigned short* A,
                                                 const unsigned short* Bt,
                                                 const float* bias,
                                                 unsigned short* C, int M,
                                                 int N, int K) {
  mgemm_body<0>(A, Bt, bias, C, M, N, K, nullptr, nullptr);
}
__global__ __launch_bounds__(256, 2) void dec3_k(const unsigned short* A,
                                                 const unsigned short* Bt,
                                                 const float* bias, float* C,
                                                 int M, int N, int K,
                                                 const float* xref,
                                                 double* accums) {
  mgemm_body<1>(A, Bt, bias, C, M, N, K, xref, accums);
}

// transpose-cast fp32 [K][N] -> bf16 [N][K]
__global__ void castT_k(const float* __restrict__ W,
                        unsigned short* __restrict__ out, int K, int N) {
  __shared__ float t[32][33];
  const int tx = threadIdx.x & 31, ty4 = threadIdx.x >> 5;
  const int nb = blockIdx.x << 5, kb = blockIdx.y << 5;
#pragma unroll
  for (int r = 0; r < 4; ++r) {
    const int k = (ty4 << 2) + r;
    t[k][tx] = W[(size_t)(kb + k) * N + nb + tx];
  }
  __syncthreads();
#pragma unroll
  for (int r = 0; r < 4; ++r) {
    const int n = (ty4 << 2) + r;
    out[(size_t)(nb + n) * K + kb + tx] = f2b(t[tx][n]);
  }
}

__global__ void rowsumsq(const float* __restrict__ v, float* __restrict__ out,
                         int rows) {
  const int w = (int)((blockIdx.x * blockDim.x + threadIdx.x) >> 6);
  const int lane = threadIdx.x & 63;
  if (w >= rows) return;
  const float4 x = *(const float4*)(v + (size_t)w * 256 + (lane << 2));
  float s = ((x.x * x.x + x.y * x.y) + x.z * x.z) + x.w * x.w;
#pragma unroll
  for (int o = 32; o; o >>= 1) s += __shfl_down(s, o);
  if (lane == 0) out[w] = s;
}

__global__ void finalize_vq(const unsigned long long* __restrict__ keys,
                            const float* __restrict__ z,
                            const float* __restrict__ cb,
                            unsigned short* __restrict__ qst_bf,
                            float* __restrict__ tok, int* __restrict__ counts,
                            double* __restrict__ accums) {
  const int row = (int)((blockIdx.x * blockDim.x + threadIdx.x) >> 6);
  const int lane = threadIdx.x & 63;
  if (row >= B_N) return;
  const int idx = (int)(keys[row] & 0xffffffffull);
  const float4 zv = *(const float4*)(z + (size_t)row * 256 + (lane << 2));
  const float4 evv = *(const float4*)(cb + (size_t)idx * 256 + (lane << 2));
  float4 q;
  double s = 0.0;
  float d;
  d = evv.x - zv.x; q.x = zv.x + d; s += (double)d * (double)d;
  d = evv.y - zv.y; q.y = zv.y + d; s += (double)d * (double)d;
  d = evv.z - zv.z; q.z = zv.z + d; s += (double)d * (double)d;
  d = evv.w - zv.w; q.w = zv.w + d; s += (double)d * (double)d;
  ushort4 qb;
  qb.x = f2b(q.x); qb.y = f2b(q.y); qb.z = f2b(q.z); qb.w = f2b(q.w);
  *(ushort4*)(qst_bf + (size_t)row * 256 + (lane << 2)) = qb;
#pragma unroll
  for (int o = 32; o; o >>= 1) s += __shfl_down(s, o);
  if (lane == 0) {
    atomicAdd(accums + 0, s);
    tok[row] = (float)idx;
    atomicAdd(counts + idx, 1);
  }
}

__global__ void finalize_scalars(const int* __restrict__ counts,
                                 const double* __restrict__ accums,
                                 float* __restrict__ outs) {
  __shared__ double red[256];
  double h = 0.0;
  for (int k = threadIdx.x; k < K_CB; k += 256) {
    const float p = (float)counts[k] * (1.0f / 8192.0f);
    const float t = p * logf(p + 1e-10f);
    h += (double)t;
  }
  red[threadIdx.x] = h;
  __syncthreads();
  for (int s = 128; s; s >>= 1) {
    if ((int)threadIdx.x < s) red[threadIdx.x] += red[threadIdx.x + s];
    __syncthreads();
  }
  if (threadIdx.x == 0) {
    const float perp = expf((float)(-red[0]));
    const float m1 = (float)(accums[0] * (1.0 / ((double)B_N * (double)D_LAT)));
    const float vq = m1 + 0.25f * m1;
    const float rl = (float)(accums[1] * (1.0 / ((double)B_N * (double)D_IN)));
    outs[0] = vq;
    outs[1] = rl;
    outs[2] = vq + rl;
    outs[3] = perp;
  }
}

extern "C" void kernel_launch(void* const* d_in, const int* in_sizes, int n_in,
                              void* d_out, int out_size, void* d_ws,
                              size_t ws_size, hipStream_t stream) {
  (void)in_sizes; (void)n_in; (void)out_size;
  const float* x   = (const float*)d_in[0];
  const float* eW1 = (const float*)d_in[1];
  const float* eb1 = (const float*)d_in[2];
  const float* eW2 = (const float*)d_in[3];
  const float* eb2 = (const float*)d_in[4];
  const float* eW3 = (const float*)d_in[5];
  const float* eb3 = (const float*)d_in[6];
  const float* cb  = (const float*)d_in[7];
  const float* dW1 = (const float*)d_in[8];
  const float* db1 = (const float*)d_in[9];
  const float* dW2 = (const float*)d_in[10];
  const float* db2 = (const float*)d_in[11];
  const float* dW3 = (const float*)d_in[12];
  const float* db3 = (const float*)d_in[13];
  float* out = (float*)d_out;

  char* ws = (char*)d_ws;
  const size_t OFF_Z      = 0;
  const size_t OFF_EEV    = OFF_Z + (size_t)B_N * D_LAT * 4;
  const size_t OFF_ZZV    = OFF_EEV + (size_t)K_CB * 4;
  const size_t OFF_KEYS   = OFF_ZZV + (size_t)B_N * 4;
  const size_t OFF_COUNTS = OFF_KEYS + (size_t)B_N * 8;
  const size_t OFF_ACC    = OFF_COUNTS + (size_t)K_CB * 4;
  const size_t OFF_QB     = OFF_ACC + 256;
  const size_t OFF_K2     = OFF_QB + (size_t)B_N * D_LAT * 2;
  const size_t OFF_H      = OFF_K2 + (size_t)B_N * VQ_NB * 8;

  float* z    = (float*)(ws + OFF_Z);
  float* eev  = (float*)(ws + OFF_EEV);
  float* zzv  = (float*)(ws + OFF_ZZV);
  unsigned long long* keys = (unsigned long long*)(ws + OFF_KEYS);
  int* counts = (int*)(ws + OFF_COUNTS);
  double* accums = (double*)(ws + OFF_ACC);
  unsigned short* qst_bf = (unsigned short*)(ws + OFF_QB);
  unsigned long long* keys2 = (unsigned long long*)(ws + OFF_K2);

  const size_t SZ_XT = (size_t)D_IN * B_N * 4;  // 32MB
  int cA = 0;
  for (int c = 8192; c >= 1024; c >>= 1)
    if (OFF_H + SZ_XT + 2ull * c * D_HID * 4 <= ws_size) { cA = c; break; }

  int c_enc = 256;
  for (int c = 8192; c >= 256; c >>= 1)
    if (OFF_H + 2ull * c * D_HID * 4 <= ws_size) { c_enc = c; break; }

  const size_t SZ_WB1 = (size_t)D_HID * D_LAT * 2;
  const size_t SZ_WB2 = (size_t)D_HID * D_HID * 2;
  const size_t SZ_WB3 = (size_t)D_IN * D_HID * 2;
  const size_t OFF_DECH = OFF_H + SZ_WB1 + SZ_WB2 + SZ_WB3;
  int c_dec = 128;
  for (int c = 8192; c >= 128; c >>= 1)
    if (OFF_DECH + 2ull * c * D_HID * 2 <= ws_size) { c_dec = c; break; }
  unsigned short* wB1 = (unsigned short*)(ws + OFF_H);
  unsigned short* wB2 = (unsigned short*)(ws + OFF_H + SZ_WB1);
  unsigned short* wB3 = (unsigned short*)(ws + OFF_H + SZ_WB1 + SZ_WB2);
  unsigned short* hbfA = (unsigned short*)(ws + OFF_DECH);
  unsigned short* hbfB = hbfA + (size_t)c_dec * D_HID;

  float* tok_out = out + (size_t)B_N * D_IN;
  float* scal_out = tok_out + B_N;

  hipMemsetAsync(counts, 0, (size_t)K_CB * 4, stream);
  hipMemsetAsync(accums, 0, 2 * sizeof(double), stream);

  rowsumsq<<<(K_CB * 64) / 256, 256, 0, stream>>>(cb, eev, K_CB);

  float* zT;
  float* cbT;
  if (cA >= 4096) {
    // ---- encoder, A^T-chained & chunked (bit-identical chain) ----
    float* xT = (float*)(ws + OFF_H);          // [1024][8192] 32MB
    float* hAT = xT + (size_t)D_IN * B_N;      // [4096][cA]
    float* hBT = hAT + (size_t)D_HID * cA;     // [4096][cA]
    float* P3 = hAT;                           // split-K partials (hAT dead)
    transF_k<<<dim3(D_IN / 32, B_N / 32), 256, 0, stream>>>(x, xT, B_N, D_IN);
    for (int c0 = 0; c0 < B_N; c0 += cA) {
      enc1_k<<<dim3(D_HID / 128, cA / 256), 256, 0, stream>>>(
          xT, eW1, eb1, hAT, B_N, c0, cA, D_HID, D_IN);
      enc2_k<<<dim3(D_HID / 128, cA / 256), 256, 0, stream>>>(
          hAT, eW2, eb2, hBT, cA, 0, cA, D_HID, D_HID);
      enc3_part_k<true><<<dim3(D_LAT / 128, cA / 128, 8), 256, 0, stream>>>(
          hBT, eW3, P3, cA, D_HID, cA);
      enc3_comb_k<<<(cA * (D_LAT / 4) + 255) / 256, 256, 0, stream>>>(
          P3, eb3, z + (size_t)c0 * D_LAT, cA);
    }
    zT = xT;                                    // 8MB (xT dead)
    cbT = xT + (size_t)D_LAT * B_N;             // 16MB
  } else {
    float* hA = (float*)(ws + OFF_H);
    float* hB = hA + (size_t)c_enc * D_HID;
    float* P3 = hA;
    for (int c0 = 0; c0 < B_N; c0 += c_enc) {
      const dim3 gH(D_HID / 128, c_enc / 128);
      enc_small_k<<<gH, 256, 0, stream>>>(x + (size_t)c0 * D_IN, eW1, eb1, hA,
                                          c_enc, D_HID, D_IN);
      enc_small_k<<<gH, 256, 0, stream>>>(hA, eW2, eb2, hB, c_enc, D_HID,
                                          D_HID);
      enc3_part_k<false><<<dim3(D_LAT / 128, c_enc / 128, 8), 256, 0, stream>>>(
          hB, eW3, P3, c_enc, D_HID, 0);
      enc3_comb_k<<<(c_enc * (D_LAT / 4) + 255) / 256, 256, 0, stream>>>(
          P3, eb3, z + (size_t)c0 * D_LAT, c_enc);
    }
    zT = hA;
    cbT = hB;
  }

  // ---- VQ prep: z^T, cb^T (into now-dead encoder buffers) ----
  transF_k<<<dim3(D_LAT / 32, B_N / 32), 256, 0, stream>>>(z, zT, B_N, D_LAT);
  transF_k<<<dim3(D_LAT / 32, K_CB / 32), 256, 0, stream>>>(cb, cbT, K_CB,
                                                            D_LAT);
  rowsumsq<<<(B_N * 64) / 256, 256, 0, stream>>>(z, zzv, B_N);

  // ---- VQ (atomic-free 2-stage) ----
  vq_k256<<<dim3(VQ_NB, B_N / 256), 256, 0, stream>>>(zT, cbT, zzv, eev, keys2);
  vq_red_k<<<(B_N * 64) / 256, 256, 0, stream>>>(keys2, keys);
  finalize_vq<<<(B_N * 64) / 256, 256, 0, stream>>>(keys, z, cb, qst_bf,
                                                    tok_out, counts, accums);

  // ---- decoder weight transpose-casts ----
  castT_k<<<dim3(D_HID / 32, D_LAT / 32), 256, 0, stream>>>(dW1, wB1, D_LAT, D_HID);
  castT_k<<<dim3(D_HID / 32, D_HID / 32), 256, 0, stream>>>(dW2, wB2, D_HID, D_HID);
  castT_k<<<dim3(D_IN / 32, D_HID / 32), 256, 0, stream>>>(dW3, wB3, D_HID, D_IN);

  // ---- decoder (bf16 MFMA) ----
  for (int c0 = 0; c0 < B_N; c0 += c_dec) {
    const dim3 gH(D_HID / 128, c_dec / 128);
    dec1_k<<<gH, 256, 0, stream>>>(qst_bf + (size_t)c0 * D_LAT, wB1, db1, hbfA,
                                   c_dec, D_HID, D_LAT);
    dec2_k<<<gH, 256, 0, stream>>>(hbfA, wB2, db2, hbfB, c_dec, D_HID, D_HID);
    dec3_k<<<dim3(D_IN / 128, c_dec / 128), 256, 0, stream>>>(
        hbfB, wB3, db3, out + (size_t)c0 * D_IN, c_dec, D_IN, D_HID,
        x + (size_t)c0 * D_IN, accums);
  }

  finalize_scalars<<<1, 256, 0, stream>>>(counts, accums, scal_out);
}